// Round 6
// baseline (522.845 us; speedup 1.0000x reference)
//
#include <hip/hip_runtime.h>
#include <math.h>

#define B_   32
#define N_   8192
#define H_   128
#define G_   10
#define TOKS (B_*N_)
#define THREADS 512
#define WAVES 8
#define TPW 32
#define TPB 256
#define LDW 136   // hids row stride in shorts (272B)

typedef short bf16x8 __attribute__((ext_vector_type(8)));
typedef short bf16x4 __attribute__((ext_vector_type(4)));
typedef float f32x4 __attribute__((ext_vector_type(4)));

// ws layout: [0..1] loss_sum/mask_count floats; weight image at byte WS_IMG_OFF.
//   w1img [3][128][128]  W1^T: [h][j][i]
//   w2img [3][16][128]   W2^T: [h][g pad16][k]
//   b1img [3][128] f32, b2img [3][16] f32
#define WS_IMG_OFF 256
#define IMG_W2   (3*H_*H_)
#define IMG_BF   (IMG_W2 + 3*16*H_)   // float region start (in shorts)
#define IMG_BYTES (IMG_BF*2 + 3*H_*4 + 3*16*4)

__device__ __forceinline__ short f2bf(float f) {
  union { float f; unsigned u; } v; v.f = f;
  unsigned r = v.u + 0x7fffu + ((v.u >> 16) & 1u);  // RNE
  return (short)(r >> 16);
}

__global__ __launch_bounds__(64) void init_kernel(float* out, float* ws) {
  int t = threadIdx.x;
  if (t < 33) out[t] = 0.0f;
  if (t < 2)  ws[t]  = 0.0f;
}

__global__ __launch_bounds__(64) void fin_kernel(float* out, const float* ws) {
  if (threadIdx.x == 0) out[32] = ws[0] / fmaxf(ws[1], 1.0f);
}

__global__ __launch_bounds__(256) void prep_kernel(
    const float* __restrict__ w1_0, const float* __restrict__ b1_0,
    const float* __restrict__ w2_0, const float* __restrict__ b2_0,
    const float* __restrict__ w1_1, const float* __restrict__ b1_1,
    const float* __restrict__ w2_1, const float* __restrict__ b2_1,
    const float* __restrict__ w1_2, const float* __restrict__ b1_2,
    const float* __restrict__ w2_2, const float* __restrict__ b2_2,
    short* __restrict__ img) {
  const float* w1p[3] = {w1_0, w1_1, w1_2};
  const float* w2p[3] = {w2_0, w2_1, w2_2};
  const float* b1p[3] = {b1_0, b1_1, b1_2};
  const float* b2p[3] = {b2_0, b2_1, b2_2};
  int t = blockIdx.x * 256 + threadIdx.x;
  int stride = gridDim.x * 256;
  for (int idx = t; idx < 3*H_*H_; idx += stride) {
    int h = idx / (H_*H_), rem = idx - h*(H_*H_);
    int j = rem >> 7, i = rem & 127;
    img[idx] = f2bf(w1p[h][i*H_ + j]);          // W1^T
  }
  for (int idx = t; idx < 3*16*H_; idx += stride) {
    int h = idx / (16*H_), rem = idx - h*(16*H_);
    int g = rem >> 7, k = rem & 127;
    img[IMG_W2 + idx] = (g < G_) ? f2bf(w2p[h][k*G_ + g]) : (short)0;
  }
  float* bimg = (float*)(img + IMG_BF);
  if (t < 3*H_ + 3*16) {
    if (t < 3*H_) { int h = t >> 7, j = t & 127; bimg[t] = b1p[h][j]; }
    else { int i2 = t - 3*H_; int h = i2 >> 4, g = i2 & 15;
           bimg[t] = (g < G_) ? b2p[h][g] : 0.0f; }
  }
}

template<int PREP>
__global__ __launch_bounds__(THREADS, 4)   // cap 128 VGPR -> 4 waves/EU, no spills
void rtm_main(const float* __restrict__ feat,
              const float* __restrict__ dist,
              const int* __restrict__ dmask,
              const short* __restrict__ img,
              const float* __restrict__ w1_0, const float* __restrict__ b1_0,
              const float* __restrict__ w2_0, const float* __restrict__ b2_0,
              const float* __restrict__ w1_1, const float* __restrict__ b1_1,
              const float* __restrict__ w2_1, const float* __restrict__ b2_1,
              const float* __restrict__ w1_2, const float* __restrict__ b1_2,
              const float* __restrict__ w2_2, const float* __restrict__ b2_2,
              float* __restrict__ out, float* __restrict__ ws) {
  __shared__ short hids[WAVES][16][LDW];   // [wave][token][j]
  __shared__ float red[WAVES][3];

  const int tid  = threadIdx.x;
  const int wave = tid >> 6;
  const int lane = tid & 63;
  const int q  = lane >> 4;
  const int lg = lane & 15;
  const long wtok0 = (long)blockIdx.x * TPB + (long)wave * TPW;

  const float* bimg = PREP ? (const float*)(img + IMG_BF) : nullptr;
  const float* w1p[3] = {w1_0, w1_1, w1_2};
  const float* w2p[3] = {w2_0, w2_1, w2_2};
  const float* b1p[3] = {b1_0, b1_1, b1_2};
  const float* b2p[3] = {b2_0, b2_1, b2_2};

  float* out_score = out;
  float* out_pi = out + 33;
  float* out_mu = out + 33 + (size_t)TOKS*G_;
  float* out_sg = out + 33 + 2*(size_t)TOKS*G_;
  const float HLOG2PI = 0.91893853320467274f;
  const bool v0 = (q*4+0) < G_, v1 = (q*4+1) < G_, v2 = (q*4+2) < G_, v3 = (q*4+3) < G_;

  float accP = 0.f, accL = 0.f, accC = 0.f;

  // ---- process the two 16-token tiles fully sequentially (small live set) ----
#pragma unroll
  for (int mt = 0; mt < 2; ++mt) {
    const long tok = wtok0 + mt*16 + lg;
    float d  = dist[tok];
    int   mi = dmask[tok];

    // features -> bf16 B-fragments: lane holds B[k=(lane>>4)*8+e][tok=lane&15]
    bf16x8 a1[4];
    {
      const float* fr = feat + tok * (long)H_;
#pragma unroll
      for (int c = 0; c < 4; ++c) {
        const float4* p = reinterpret_cast<const float4*>(fr + c*32 + q*8);
        float4 lo = p[0], hi = p[1];
        bf16x8 a;
        a[0]=f2bf(lo.x); a[1]=f2bf(lo.y); a[2]=f2bf(lo.z); a[3]=f2bf(lo.w);
        a[4]=f2bf(hi.x); a[5]=f2bf(hi.y); a[6]=f2bf(hi.z); a[7]=f2bf(hi.w);
        a1[c] = a;
      }
    }

    f32x4 lgt[3];
#pragma unroll
    for (int h = 0; h < 3; ++h) {
      // layer 1: W1^T fragments straight from L1/L2-resident image
      f32x4 acc[8];
#pragma unroll
      for (int nt = 0; nt < 8; ++nt) acc[nt] = (f32x4){0.f,0.f,0.f,0.f};
#pragma unroll
      for (int c = 0; c < 4; ++c) {
#pragma unroll
        for (int nt = 0; nt < 8; ++nt) {
          bf16x8 wfr;
          if constexpr (PREP) {
            wfr = *reinterpret_cast<const bf16x8*>(&img[(h*H_ + nt*16 + lg)*H_ + c*32 + q*8]);
          } else {
#pragma unroll
            for (int e = 0; e < 8; ++e)
              wfr[e] = f2bf(w1p[h][(c*32 + q*8 + e)*H_ + nt*16 + lg]);
          }
          acc[nt] = __builtin_amdgcn_mfma_f32_16x16x32_bf16(wfr, a1[c], acc[nt], 0, 0, 0);
        }
      }
      // bias+relu+pack: D row = j = q*4+r (contiguous), col = token = lg
#pragma unroll
      for (int nt = 0; nt < 8; ++nt) {
        f32x4 b1v;
        if constexpr (PREP) {
          b1v = *reinterpret_cast<const f32x4*>(&bimg[h*H_ + nt*16 + q*4]);
        } else {
#pragma unroll
          for (int r = 0; r < 4; ++r) b1v[r] = b1p[h][nt*16 + q*4 + r];
        }
        bf16x4 pk;
#pragma unroll
        for (int r = 0; r < 4; ++r)
          pk[r] = f2bf(fmaxf(acc[nt][r] + b1v[r], 0.0f));
        *reinterpret_cast<bf16x4*>(&hids[wave][lg][nt*16 + q*4]) = pk;
      }
      // layer 2 (same-wave LDS FIFO ordering; no barrier needed)
      f32x4 lacc = (f32x4){0.f,0.f,0.f,0.f};
#pragma unroll
      for (int c = 0; c < 4; ++c) {
        bf16x8 w2fr;
        if constexpr (PREP) {
          w2fr = *reinterpret_cast<const bf16x8*>(&img[IMG_W2 + (h*16 + lg)*H_ + c*32 + q*8]);
        } else {
          bf16x8 t;
#pragma unroll
          for (int e = 0; e < 8; ++e)
            t[e] = (lg < G_) ? f2bf(w2p[h][(c*32 + q*8 + e)*G_ + lg]) : (short)0;
          w2fr = t;
        }
        bf16x8 hfr = *reinterpret_cast<const bf16x8*>(&hids[wave][lg][c*32 + q*8]);
        lacc = __builtin_amdgcn_mfma_f32_16x16x32_bf16(w2fr, hfr, lacc, 0, 0, 0);
      }
      f32x4 b2v;
      if constexpr (PREP) {
        b2v = *reinterpret_cast<const f32x4*>(&bimg[3*H_ + h*16 + q*4]);
      } else {
#pragma unroll
        for (int r = 0; r < 4; ++r) b2v[r] = (q*4+r < G_) ? b2p[h][q*4+r] : 0.0f;
      }
      lgt[h] = lacc + b2v;   // row = g = q*4+r, col = token = lg
    }

    // ---- epilogue for this tile: token = lg; lane holds g = q*4+r ----
    bool mk = (mi != 0) && (d <= 8.0f);
    f32x4 LP = lgt[0], LS = lgt[1], LM = lgt[2];

    float vm = v0 ? LP[0] : -INFINITY;
    if (v1) vm = fmaxf(vm, LP[1]);
    if (v2) vm = fmaxf(vm, LP[2]);
    if (v3) vm = fmaxf(vm, LP[3]);
    vm = fmaxf(vm, __shfl_xor(vm, 16));
    vm = fmaxf(vm, __shfl_xor(vm, 32));
    float e0 = v0 ? __expf(LP[0]-vm) : 0.f;
    float e1 = v1 ? __expf(LP[1]-vm) : 0.f;
    float e2 = v2 ? __expf(LP[2]-vm) : 0.f;
    float e3 = v3 ? __expf(LP[3]-vm) : 0.f;
    float s = e0+e1+e2+e3;
    s += __shfl_xor(s, 16);
    s += __shfl_xor(s, 32);
    float inv = 1.0f / s;
    float pi[4] = {e0*inv, e1*inv, e2*inv, e3*inv};

    float sg[4], mu[4], ll[4];
#pragma unroll
    for (int r = 0; r < 4; ++r) {
      sg[r] = (LS[r] > 0.f) ? (LS[r] + 1.4f) : (__expf(LS[r]) + 0.4f);
      mu[r] = (LM[r] > 0.f) ? (LM[r] + 1.0f) : __expf(LM[r]);
      float z = (d - mu[r]) / sg[r];
      ll[r] = -0.5f*z*z - __logf(sg[r]) - HLOG2PI;
    }

    if (q*4 < G_) {
      size_t o = (size_t)tok*G_ + q*4;
      *reinterpret_cast<float2*>(&out_pi[o]) = make_float2(pi[0], pi[1]);
      *reinterpret_cast<float2*>(&out_mu[o]) = make_float2(mu[0], mu[1]);
      *reinterpret_cast<float2*>(&out_sg[o]) = make_float2(sg[0], sg[1]);
      if (q*4+2 < G_) {
        *reinterpret_cast<float2*>(&out_pi[o+2]) = make_float2(pi[2], pi[3]);
        *reinterpret_cast<float2*>(&out_mu[o+2]) = make_float2(mu[2], mu[3]);
        *reinterpret_cast<float2*>(&out_sg[o+2]) = make_float2(sg[2], sg[3]);
      }
    }

    float a0 = v0 ? (__logf(pi[0]+1e-10f) + ll[0]) : -INFINITY;
    float a1x= v1 ? (__logf(pi[1]+1e-10f) + ll[1]) : -INFINITY;
    float a2 = v2 ? (__logf(pi[2]+1e-10f) + ll[2]) : -INFINITY;
    float a3 = v3 ? (__logf(pi[3]+1e-10f) + ll[3]) : -INFINITY;
    float m2 = fmaxf(fmaxf(a0,a1x), fmaxf(a2,a3));
    m2 = fmaxf(m2, __shfl_xor(m2, 16));
    m2 = fmaxf(m2, __shfl_xor(m2, 32));
    float s2 = (v0?__expf(a0-m2):0.f) + (v1?__expf(a1x-m2):0.f)
             + (v2?__expf(a2-m2):0.f) + (v3?__expf(a3-m2):0.f);
    s2 += __shfl_xor(s2, 16);
    s2 += __shfl_xor(s2, 32);
    float closs = -(m2 + __logf(s2));

    float s3 = (v0?__expf(ll[0])*pi[0]:0.f) + (v1?__expf(ll[1])*pi[1]:0.f)
             + (v2?__expf(ll[2])*pi[2]:0.f) + (v3?__expf(ll[3])*pi[3]:0.f);
    s3 += __shfl_xor(s3, 16);
    s3 += __shfl_xor(s3, 32);
    float prob = s3 / (d*d + 1e-10f);

    if (lane < 16 && mk) { accP += prob; accL += closs; accC += 1.f; }
  }

  accP += __shfl_xor(accP, 1); accP += __shfl_xor(accP, 2);
  accP += __shfl_xor(accP, 4); accP += __shfl_xor(accP, 8);
  accL += __shfl_xor(accL, 1); accL += __shfl_xor(accL, 2);
  accL += __shfl_xor(accL, 4); accL += __shfl_xor(accL, 8);
  accC += __shfl_xor(accC, 1); accC += __shfl_xor(accC, 2);
  accC += __shfl_xor(accC, 4); accC += __shfl_xor(accC, 8);
  if (lane == 0) { red[wave][0] = accP; red[wave][1] = accL; red[wave][2] = accC; }
  __syncthreads();
  if (tid == 0) {
    float sP = 0.f, sL = 0.f, sC = 0.f;
    for (int w = 0; w < WAVES; ++w) { sP += red[w][0]; sL += red[w][1]; sC += red[w][2]; }
    int b = (int)(((long)blockIdx.x * TPB) >> 13);
    atomicAdd(&out_score[b], sP);
    atomicAdd(&ws[0], sL);
    atomicAdd(&ws[1], sC);
  }
}

extern "C" void kernel_launch(void* const* d_in, const int* in_sizes, int n_in,
                              void* d_out, int out_size, void* d_ws, size_t ws_size,
                              hipStream_t stream) {
  const float* feat = (const float*)d_in[0];
  const float* dist = (const float*)d_in[1];
  const int* dmask = (const int*)d_in[2];
  float* out = (float*)d_out;
  float* ws  = (float*)d_ws;

  hipLaunchKernelGGL(init_kernel, dim3(1), dim3(64), 0, stream, out, ws);

  bool prep_ok = (ws_size >= (size_t)(WS_IMG_OFF + IMG_BYTES));
  if (prep_ok) {
    short* img = (short*)((char*)d_ws + WS_IMG_OFF);
    hipLaunchKernelGGL(prep_kernel, dim3(116), dim3(256), 0, stream,
        (const float*)d_in[3],  (const float*)d_in[4],  (const float*)d_in[5],  (const float*)d_in[6],
        (const float*)d_in[7],  (const float*)d_in[8],  (const float*)d_in[9],  (const float*)d_in[10],
        (const float*)d_in[11], (const float*)d_in[12], (const float*)d_in[13], (const float*)d_in[14],
        img);
    hipLaunchKernelGGL((rtm_main<1>), dim3(TOKS/TPB), dim3(THREADS), 0, stream,
        feat, dist, dmask, (const short*)img,
        (const float*)d_in[3],  (const float*)d_in[4],  (const float*)d_in[5],  (const float*)d_in[6],
        (const float*)d_in[7],  (const float*)d_in[8],  (const float*)d_in[9],  (const float*)d_in[10],
        (const float*)d_in[11], (const float*)d_in[12], (const float*)d_in[13], (const float*)d_in[14],
        out, ws);
  } else {
    hipLaunchKernelGGL((rtm_main<0>), dim3(TOKS/TPB), dim3(THREADS), 0, stream,
        feat, dist, dmask, (const short*)nullptr,
        (const float*)d_in[3],  (const float*)d_in[4],  (const float*)d_in[5],  (const float*)d_in[6],
        (const float*)d_in[7],  (const float*)d_in[8],  (const float*)d_in[9],  (const float*)d_in[10],
        (const float*)d_in[11], (const float*)d_in[12], (const float*)d_in[13], (const float*)d_in[14],
        out, ws);
  }

  hipLaunchKernelGGL(fin_kernel, dim3(1), dim3(64), 0, stream, out, ws);
}

// Round 7
// 169.050 us; speedup vs baseline: 3.0928x; 3.0928x over previous
//
#include <hip/hip_runtime.h>
#include <math.h>

#define B_   32
#define N_   8192
#define H_   128
#define G_   10
#define TOKS (B_*N_)
#define THREADS 512
#define WAVES 8
#define TPW 32
#define TPB 256
#define LDW 136   // hids row stride in shorts (272B)

typedef short bf16x8 __attribute__((ext_vector_type(8)));
typedef short bf16x4 __attribute__((ext_vector_type(4)));
typedef float f32x4 __attribute__((ext_vector_type(4)));

// ws layout: [0..1] loss_sum/mask_count floats; weight image at byte WS_IMG_OFF.
//   w1img [3][128][128]  W1^T: [h][j][i]
//   w2img [3][16][128]   W2^T: [h][g pad16][k]
//   b1img [3][128] f32, b2img [3][16] f32
#define WS_IMG_OFF 256
#define IMG_W2   (3*H_*H_)
#define IMG_BF   (IMG_W2 + 3*16*H_)   // float region start (in shorts)
#define IMG_BYTES (IMG_BF*2 + 3*H_*4 + 3*16*4)

__device__ __forceinline__ short f2bf(float f) {
  union { float f; unsigned u; } v; v.f = f;
  unsigned r = v.u + 0x7fffu + ((v.u >> 16) & 1u);  // RNE
  return (short)(r >> 16);
}

__global__ __launch_bounds__(64) void init_kernel(float* out, float* ws) {
  int t = threadIdx.x;
  if (t < 33) out[t] = 0.0f;
  if (t < 2)  ws[t]  = 0.0f;
}

__global__ __launch_bounds__(64) void fin_kernel(float* out, const float* ws) {
  if (threadIdx.x == 0) out[32] = ws[0] / fmaxf(ws[1], 1.0f);
}

__global__ __launch_bounds__(256) void prep_kernel(
    const float* __restrict__ w1_0, const float* __restrict__ b1_0,
    const float* __restrict__ w2_0, const float* __restrict__ b2_0,
    const float* __restrict__ w1_1, const float* __restrict__ b1_1,
    const float* __restrict__ w2_1, const float* __restrict__ b2_1,
    const float* __restrict__ w1_2, const float* __restrict__ b1_2,
    const float* __restrict__ w2_2, const float* __restrict__ b2_2,
    short* __restrict__ img) {
  const float* w1p[3] = {w1_0, w1_1, w1_2};
  const float* w2p[3] = {w2_0, w2_1, w2_2};
  const float* b1p[3] = {b1_0, b1_1, b1_2};
  const float* b2p[3] = {b2_0, b2_1, b2_2};
  int t = blockIdx.x * 256 + threadIdx.x;
  int stride = gridDim.x * 256;
  for (int idx = t; idx < 3*H_*H_; idx += stride) {
    int h = idx / (H_*H_), rem = idx - h*(H_*H_);
    int j = rem >> 7, i = rem & 127;
    img[idx] = f2bf(w1p[h][i*H_ + j]);          // W1^T
  }
  for (int idx = t; idx < 3*16*H_; idx += stride) {
    int h = idx / (16*H_), rem = idx - h*(16*H_);
    int g = rem >> 7, k = rem & 127;
    img[IMG_W2 + idx] = (g < G_) ? f2bf(w2p[h][k*G_ + g]) : (short)0;
  }
  float* bimg = (float*)(img + IMG_BF);
  if (t < 3*H_ + 3*16) {
    if (t < 3*H_) { int h = t >> 7, j = t & 127; bimg[t] = b1p[h][j]; }
    else { int i2 = t - 3*H_; int h = i2 >> 4, g = i2 & 15;
           bimg[t] = (g < G_) ? b2p[h][g] : 0.0f; }
  }
}

template<int PREP>
__global__ __launch_bounds__(THREADS, 2)   // 256-reg cap: ~90 arch + ~68 acc fits, no spills
void rtm_main(const float* __restrict__ feat,
              const float* __restrict__ dist,
              const int* __restrict__ dmask,
              const short* __restrict__ img,
              const float* __restrict__ w1_0, const float* __restrict__ b1_0,
              const float* __restrict__ w2_0, const float* __restrict__ b2_0,
              const float* __restrict__ w1_1, const float* __restrict__ b1_1,
              const float* __restrict__ w2_1, const float* __restrict__ b2_1,
              const float* __restrict__ w1_2, const float* __restrict__ b1_2,
              const float* __restrict__ w2_2, const float* __restrict__ b2_2,
              float* __restrict__ out, float* __restrict__ ws) {
  __shared__ short hids[WAVES][16][LDW];   // [wave][token][j]
  __shared__ float red[WAVES][3];

  const int tid  = threadIdx.x;
  const int wave = tid >> 6;
  const int lane = tid & 63;
  const int q  = lane >> 4;
  const int lg = lane & 15;
  const long wtok0 = (long)blockIdx.x * TPB + (long)wave * TPW;

  const float* bimg = PREP ? (const float*)(img + IMG_BF) : nullptr;
  const float* w1p[3] = {w1_0, w1_1, w1_2};
  const float* w2p[3] = {w2_0, w2_1, w2_2};
  const float* b1p[3] = {b1_0, b1_1, b1_2};
  const float* b2p[3] = {b2_0, b2_1, b2_2};

  // ---- token scalars + feature fragments (convert immediately; temps die) ----
  float dpre[2]; int mpre[2];
#pragma unroll
  for (int mt = 0; mt < 2; ++mt) {
    long tok = wtok0 + mt*16 + lg;
    dpre[mt] = dist[tok];
    mpre[mt] = dmask[tok];
  }
  bf16x8 a1[2][4];   // B-fragment: lane holds B[k=(lane>>4)*8+e][tok=lane&15]
#pragma unroll
  for (int mt = 0; mt < 2; ++mt) {
    const float* fr = feat + (wtok0 + mt*16 + lg) * (long)H_;
#pragma unroll
    for (int c = 0; c < 4; ++c) {
      const float4* p = reinterpret_cast<const float4*>(fr + c*32 + q*8);
      float4 lo = p[0], hi = p[1];
      bf16x8 a;
      a[0]=f2bf(lo.x); a[1]=f2bf(lo.y); a[2]=f2bf(lo.z); a[3]=f2bf(lo.w);
      a[4]=f2bf(hi.x); a[5]=f2bf(hi.y); a[6]=f2bf(hi.z); a[7]=f2bf(hi.w);
      a1[mt][c] = a;
    }
  }

  // ---- 3 heads; W1 fragment read once feeds both M-tiles ----
  f32x4 lgt[3][2];
#pragma unroll
  for (int h = 0; h < 3; ++h) {
    f32x4 acc[2][8];
#pragma unroll
    for (int mt = 0; mt < 2; ++mt)
#pragma unroll
      for (int nt = 0; nt < 8; ++nt) acc[mt][nt] = (f32x4){0.f,0.f,0.f,0.f};
#pragma unroll
    for (int c = 0; c < 4; ++c) {
#pragma unroll
      for (int nt = 0; nt < 8; ++nt) {
        bf16x8 wfr;
        if constexpr (PREP) {
          wfr = *reinterpret_cast<const bf16x8*>(&img[(h*H_ + nt*16 + lg)*H_ + c*32 + q*8]);
        } else {
#pragma unroll
          for (int e = 0; e < 8; ++e)
            wfr[e] = f2bf(w1p[h][(c*32 + q*8 + e)*H_ + nt*16 + lg]);
        }
        acc[0][nt] = __builtin_amdgcn_mfma_f32_16x16x32_bf16(wfr, a1[0][c], acc[0][nt], 0, 0, 0);
        acc[1][nt] = __builtin_amdgcn_mfma_f32_16x16x32_bf16(wfr, a1[1][c], acc[1][nt], 0, 0, 0);
      }
    }

#pragma unroll
    for (int mt = 0; mt < 2; ++mt) {
      // bias+relu+pack: D row = j = q*4+r (contiguous), col = token = lg
#pragma unroll
      for (int nt = 0; nt < 8; ++nt) {
        f32x4 b1v;
        if constexpr (PREP) {
          b1v = *reinterpret_cast<const f32x4*>(&bimg[h*H_ + nt*16 + q*4]);
        } else {
#pragma unroll
          for (int r = 0; r < 4; ++r) b1v[r] = b1p[h][nt*16 + q*4 + r];
        }
        bf16x4 pk;
#pragma unroll
        for (int r = 0; r < 4; ++r)
          pk[r] = f2bf(fmaxf(acc[mt][nt][r] + b1v[r], 0.0f));
        *reinterpret_cast<bf16x4*>(&hids[wave][lg][nt*16 + q*4]) = pk;
      }
      // layer 2 (same-wave LDS FIFO ordering; no barrier needed)
      f32x4 lacc = (f32x4){0.f,0.f,0.f,0.f};
#pragma unroll
      for (int c = 0; c < 4; ++c) {
        bf16x8 w2fr;
        if constexpr (PREP) {
          w2fr = *reinterpret_cast<const bf16x8*>(&img[IMG_W2 + (h*16 + lg)*H_ + c*32 + q*8]);
        } else {
          bf16x8 t;
#pragma unroll
          for (int e = 0; e < 8; ++e)
            t[e] = (lg < G_) ? f2bf(w2p[h][(c*32 + q*8 + e)*G_ + lg]) : (short)0;
          w2fr = t;
        }
        bf16x8 hfr = *reinterpret_cast<const bf16x8*>(&hids[wave][lg][c*32 + q*8]);
        lacc = __builtin_amdgcn_mfma_f32_16x16x32_bf16(w2fr, hfr, lacc, 0, 0, 0);
      }
      f32x4 b2v;
      if constexpr (PREP) {
        b2v = *reinterpret_cast<const f32x4*>(&bimg[3*H_ + h*16 + q*4]);
      } else {
#pragma unroll
        for (int r = 0; r < 4; ++r) b2v[r] = (q*4+r < G_) ? b2p[h][q*4+r] : 0.0f;
      }
      lgt[h][mt] = lacc + b2v;   // row = g = q*4+r, col = token = lg
    }
  }

  // ---- epilogue: token = lg; lane holds g = q*4+r ----
  float* out_score = out;
  float* out_pi = out + 33;
  float* out_mu = out + 33 + (size_t)TOKS*G_;
  float* out_sg = out + 33 + 2*(size_t)TOKS*G_;
  const float HLOG2PI = 0.91893853320467274f;
  const bool v0 = (q*4+0) < G_, v1 = (q*4+1) < G_, v2 = (q*4+2) < G_, v3 = (q*4+3) < G_;

  float accP = 0.f, accL = 0.f, accC = 0.f;
#pragma unroll
  for (int mt = 0; mt < 2; ++mt) {
    long tok = wtok0 + mt*16 + lg;
    float d  = dpre[mt];
    bool  mk = (mpre[mt] != 0) && (d <= 8.0f);

    f32x4 LP = lgt[0][mt], LS = lgt[1][mt], LM = lgt[2][mt];

    float vm = v0 ? LP[0] : -INFINITY;
    if (v1) vm = fmaxf(vm, LP[1]);
    if (v2) vm = fmaxf(vm, LP[2]);
    if (v3) vm = fmaxf(vm, LP[3]);
    vm = fmaxf(vm, __shfl_xor(vm, 16));
    vm = fmaxf(vm, __shfl_xor(vm, 32));
    float e0 = v0 ? __expf(LP[0]-vm) : 0.f;
    float e1 = v1 ? __expf(LP[1]-vm) : 0.f;
    float e2 = v2 ? __expf(LP[2]-vm) : 0.f;
    float e3 = v3 ? __expf(LP[3]-vm) : 0.f;
    float s = e0+e1+e2+e3;
    s += __shfl_xor(s, 16);
    s += __shfl_xor(s, 32);
    float inv = 1.0f / s;
    float pi[4] = {e0*inv, e1*inv, e2*inv, e3*inv};

    float sg[4], mu[4], ll[4];
#pragma unroll
    for (int r = 0; r < 4; ++r) {
      sg[r] = (LS[r] > 0.f) ? (LS[r] + 1.4f) : (__expf(LS[r]) + 0.4f);
      mu[r] = (LM[r] > 0.f) ? (LM[r] + 1.0f) : __expf(LM[r]);
      float z = (d - mu[r]) / sg[r];
      ll[r] = -0.5f*z*z - __logf(sg[r]) - HLOG2PI;
    }

    if (q*4 < G_) {
      size_t o = (size_t)tok*G_ + q*4;
      *reinterpret_cast<float2*>(&out_pi[o]) = make_float2(pi[0], pi[1]);
      *reinterpret_cast<float2*>(&out_mu[o]) = make_float2(mu[0], mu[1]);
      *reinterpret_cast<float2*>(&out_sg[o]) = make_float2(sg[0], sg[1]);
      if (q*4+2 < G_) {
        *reinterpret_cast<float2*>(&out_pi[o+2]) = make_float2(pi[2], pi[3]);
        *reinterpret_cast<float2*>(&out_mu[o+2]) = make_float2(mu[2], mu[3]);
        *reinterpret_cast<float2*>(&out_sg[o+2]) = make_float2(sg[2], sg[3]);
      }
    }

    float a0 = v0 ? (__logf(pi[0]+1e-10f) + ll[0]) : -INFINITY;
    float a1x= v1 ? (__logf(pi[1]+1e-10f) + ll[1]) : -INFINITY;
    float a2 = v2 ? (__logf(pi[2]+1e-10f) + ll[2]) : -INFINITY;
    float a3 = v3 ? (__logf(pi[3]+1e-10f) + ll[3]) : -INFINITY;
    float m2 = fmaxf(fmaxf(a0,a1x), fmaxf(a2,a3));
    m2 = fmaxf(m2, __shfl_xor(m2, 16));
    m2 = fmaxf(m2, __shfl_xor(m2, 32));
    float s2 = (v0?__expf(a0-m2):0.f) + (v1?__expf(a1x-m2):0.f)
             + (v2?__expf(a2-m2):0.f) + (v3?__expf(a3-m2):0.f);
    s2 += __shfl_xor(s2, 16);
    s2 += __shfl_xor(s2, 32);
    float closs = -(m2 + __logf(s2));

    float s3 = (v0?__expf(ll[0])*pi[0]:0.f) + (v1?__expf(ll[1])*pi[1]:0.f)
             + (v2?__expf(ll[2])*pi[2]:0.f) + (v3?__expf(ll[3])*pi[3]:0.f);
    s3 += __shfl_xor(s3, 16);
    s3 += __shfl_xor(s3, 32);
    float prob = s3 / (d*d + 1e-10f);

    if (lane < 16 && mk) { accP += prob; accL += closs; accC += 1.f; }
  }

  accP += __shfl_xor(accP, 1); accP += __shfl_xor(accP, 2);
  accP += __shfl_xor(accP, 4); accP += __shfl_xor(accP, 8);
  accL += __shfl_xor(accL, 1); accL += __shfl_xor(accL, 2);
  accL += __shfl_xor(accL, 4); accL += __shfl_xor(accL, 8);
  accC += __shfl_xor(accC, 1); accC += __shfl_xor(accC, 2);
  accC += __shfl_xor(accC, 4); accC += __shfl_xor(accC, 8);
  if (lane == 0) { red[wave][0] = accP; red[wave][1] = accL; red[wave][2] = accC; }
  __syncthreads();
  if (tid == 0) {
    float sP = 0.f, sL = 0.f, sC = 0.f;
    for (int w = 0; w < WAVES; ++w) { sP += red[w][0]; sL += red[w][1]; sC += red[w][2]; }
    int b = (int)(((long)blockIdx.x * TPB) >> 13);
    atomicAdd(&out_score[b], sP);
    atomicAdd(&ws[0], sL);
    atomicAdd(&ws[1], sC);
  }
}

extern "C" void kernel_launch(void* const* d_in, const int* in_sizes, int n_in,
                              void* d_out, int out_size, void* d_ws, size_t ws_size,
                              hipStream_t stream) {
  const float* feat = (const float*)d_in[0];
  const float* dist = (const float*)d_in[1];
  const int* dmask = (const int*)d_in[2];
  float* out = (float*)d_out;
  float* ws  = (float*)d_ws;

  hipLaunchKernelGGL(init_kernel, dim3(1), dim3(64), 0, stream, out, ws);

  bool prep_ok = (ws_size >= (size_t)(WS_IMG_OFF + IMG_BYTES));
  if (prep_ok) {
    short* img = (short*)((char*)d_ws + WS_IMG_OFF);
    hipLaunchKernelGGL(prep_kernel, dim3(116), dim3(256), 0, stream,
        (const float*)d_in[3],  (const float*)d_in[4],  (const float*)d_in[5],  (const float*)d_in[6],
        (const float*)d_in[7],  (const float*)d_in[8],  (const float*)d_in[9],  (const float*)d_in[10],
        (const float*)d_in[11], (const float*)d_in[12], (const float*)d_in[13], (const float*)d_in[14],
        img);
    hipLaunchKernelGGL((rtm_main<1>), dim3(TOKS/TPB), dim3(THREADS), 0, stream,
        feat, dist, dmask, (const short*)img,
        (const float*)d_in[3],  (const float*)d_in[4],  (const float*)d_in[5],  (const float*)d_in[6],
        (const float*)d_in[7],  (const float*)d_in[8],  (const float*)d_in[9],  (const float*)d_in[10],
        (const float*)d_in[11], (const float*)d_in[12], (const float*)d_in[13], (const float*)d_in[14],
        out, ws);
  } else {
    hipLaunchKernelGGL((rtm_main<0>), dim3(TOKS/TPB), dim3(THREADS), 0, stream,
        feat, dist, dmask, (const short*)nullptr,
        (const float*)d_in[3],  (const float*)d_in[4],  (const float*)d_in[5],  (const float*)d_in[6],
        (const float*)d_in[7],  (const float*)d_in[8],  (const float*)d_in[9],  (const float*)d_in[10],
        (const float*)d_in[11], (const float*)d_in[12], (const float*)d_in[13], (const float*)d_in[14],
        out, ws);
  }

  hipLaunchKernelGGL(fin_kernel, dim3(1), dim3(64), 0, stream, out, ws);
}

// Round 8
// 101.801 us; speedup vs baseline: 5.1360x; 1.6606x over previous
//
#include <hip/hip_runtime.h>
#include <math.h>

#define B_   32
#define N_   8192
#define H_   128
#define G_   10
#define TOKS (B_*N_)
#define THREADS 1024
#define WAVES 16
#define TPW 32
#define TPB 512   // tokens per block (16 waves x 32)
#define LDW 136   // padded LDS row stride in shorts (272B, 16B-aligned rows)

typedef short bf16x8 __attribute__((ext_vector_type(8)));
typedef short bf16x4 __attribute__((ext_vector_type(4)));
typedef float f32x4 __attribute__((ext_vector_type(4)));

// ws layout: [0..1] loss_sum/mask_count floats; weight image at byte WS_IMG_OFF.
#define WS_IMG_OFF 256
#define IMG_BYTES  119232          // 3*128*136*2 + 3*16*136*2 + 3*128*4 + 3*16*4
#define IMG_INSTS  117             // ceil(IMG_BYTES/1024); overshoot 576B lands in red/pad (safe)

struct __align__(16) SMem {
  // ---- first 119232 bytes == prep image, copied verbatim ----
  short w1s[3][H_][LDW];   // W1^T bf16: [head][hidden j][input i]
  short w2s[3][16][LDW];   // W2^T bf16: [head][g pad16][hidden k]
  float b1s[3][H_];
  float b2s[3][16];
  // ---- scratch (staging overshoot may scribble here pre-barrier; rewritten later) ----
  float red[WAVES][3];
  char  pad[576];
};

__device__ __forceinline__ short f2bf(float f) {
  union { float f; unsigned u; } v; v.f = f;
  unsigned r = v.u + 0x7fffu + ((v.u >> 16) & 1u);  // RNE
  return (short)(r >> 16);
}

__device__ __forceinline__ bf16x4 shfl4(bf16x4 v, int src) {
  union { bf16x4 v; int i[2]; } a, r; a.v = v;
  r.i[0] = __shfl(a.i[0], src, 64);
  r.i[1] = __shfl(a.i[1], src, 64);
  return r.v;
}

__device__ __forceinline__ void async_copy16(void* lds_uniform, const void* gsrc_perlane) {
  __builtin_amdgcn_global_load_lds(
      (const __attribute__((address_space(1))) unsigned int*)gsrc_perlane,
      (__attribute__((address_space(3))) unsigned int*)lds_uniform,
      16, 0, 0);
}

__global__ __launch_bounds__(64) void init_kernel(float* out, float* ws) {
  int t = threadIdx.x;
  if (t < 33) out[t] = 0.0f;
  if (t < 2)  ws[t]  = 0.0f;
}

__global__ __launch_bounds__(64) void fin_kernel(float* out, const float* ws) {
  if (threadIdx.x == 0) out[32] = ws[0] / fmaxf(ws[1], 1.0f);
}

__global__ __launch_bounds__(256) void prep_kernel(
    const float* __restrict__ w1_0, const float* __restrict__ b1_0,
    const float* __restrict__ w2_0, const float* __restrict__ b2_0,
    const float* __restrict__ w1_1, const float* __restrict__ b1_1,
    const float* __restrict__ w2_1, const float* __restrict__ b2_1,
    const float* __restrict__ w1_2, const float* __restrict__ b1_2,
    const float* __restrict__ w2_2, const float* __restrict__ b2_2,
    short* __restrict__ img) {
  const float* w1p[3] = {w1_0, w1_1, w1_2};
  const float* w2p[3] = {w2_0, w2_1, w2_2};
  const float* b1p[3] = {b1_0, b1_1, b1_2};
  const float* b2p[3] = {b2_0, b2_1, b2_2};
  int t = blockIdx.x * 256 + threadIdx.x;
  int stride = gridDim.x * 256;
  for (int idx = t; idx < 3*H_*LDW; idx += stride) {
    int h = idx / (H_*LDW), rem = idx - h*(H_*LDW);
    int j = rem / LDW, i = rem - j*LDW;
    img[idx] = (i < H_) ? f2bf(w1p[h][i*H_ + j]) : (short)0;
  }
  for (int idx = t; idx < 3*16*LDW; idx += stride) {
    int h = idx / (16*LDW), rem = idx - h*(16*LDW);
    int g = rem / LDW, k = rem - g*LDW;
    img[3*H_*LDW + idx] = (g < G_ && k < H_) ? f2bf(w2p[h][k*G_ + g]) : (short)0;
  }
  float* bimg = (float*)(img + 3*H_*LDW + 3*16*LDW);
  if (t < 3*H_ + 3*16) {
    if (t < 3*H_) { int h = t >> 7, j = t & 127; bimg[t] = b1p[h][j]; }
    else { int i2 = t - 3*H_; int h = i2 >> 4, g = i2 & 15;
           bimg[t] = (g < G_) ? b2p[h][g] : 0.0f; }
  }
}

template<int PREP>
__global__ __launch_bounds__(THREADS, 4)   // 1024 thr -> 4 waves/SIMD -> 128 reg cap
void rtm_main(const float* __restrict__ feat,
              const float* __restrict__ dist,
              const int* __restrict__ dmask,
              const float* __restrict__ img,
              const float* __restrict__ w1_0, const float* __restrict__ b1_0,
              const float* __restrict__ w2_0, const float* __restrict__ b2_0,
              const float* __restrict__ w1_1, const float* __restrict__ b1_1,
              const float* __restrict__ w2_1, const float* __restrict__ b2_1,
              const float* __restrict__ w1_2, const float* __restrict__ b1_2,
              const float* __restrict__ w2_2, const float* __restrict__ b2_2,
              float* __restrict__ out, float* __restrict__ ws) {
  __shared__ SMem sm;

  const int tid  = threadIdx.x;
  const int wave = tid >> 6;
  const int lane = tid & 63;
  const int q  = lane >> 4;
  const int lg = lane & 15;
  const long wtok0 = (long)blockIdx.x * TPB + (long)wave * TPW;

  // ---- token scalars + feature fragments for both tiles (pre-barrier) ----
  float dpre[2]; int mpre[2];
#pragma unroll
  for (int mt = 0; mt < 2; ++mt) {
    long tok = wtok0 + mt*16 + lg;
    dpre[mt] = dist[tok];
    mpre[mt] = dmask[tok];
  }
  bf16x8 a1[2][4];   // B-frag: lane holds B[k=(lane>>4)*8+e][tok=lane&15]
#pragma unroll
  for (int mt = 0; mt < 2; ++mt) {
    const float* fr = feat + (wtok0 + mt*16 + lg) * (long)H_;
#pragma unroll
    for (int c = 0; c < 4; ++c) {
      const float4* p = reinterpret_cast<const float4*>(fr + c*32 + q*8);
      float4 lo = p[0], hi = p[1];
      bf16x8 a;
      a[0]=f2bf(lo.x); a[1]=f2bf(lo.y); a[2]=f2bf(lo.z); a[3]=f2bf(lo.w);
      a[4]=f2bf(hi.x); a[5]=f2bf(hi.y); a[6]=f2bf(hi.z); a[7]=f2bf(hi.w);
      a1[mt][c] = a;
    }
  }

  // ---- stage weight image to LDS (async, once per CU) ----
  if constexpr (PREP) {
    char* smb = (char*)&sm;
    const char* gimg = (const char*)img;
    for (int i = wave; i < IMG_INSTS; i += WAVES)
      async_copy16(smb + i*1024, gimg + i*1024 + lane*16);
  } else {
    const float* w1p[3] = {w1_0, w1_1, w1_2};
    const float* w2p[3] = {w2_0, w2_1, w2_2};
    const float* b1p[3] = {b1_0, b1_1, b1_2};
    const float* b2p[3] = {b2_0, b2_1, b2_2};
    for (int h = 0; h < 3; ++h) {
      for (int idx = tid; idx < H_*H_; idx += THREADS) {
        int i = idx >> 7, j = idx & 127;
        sm.w1s[h][j][i] = f2bf(w1p[h][idx]);
      }
      for (int idx = tid; idx < 16*H_; idx += THREADS) {
        int g = idx >> 7, k = idx & 127;
        sm.w2s[h][g][k] = (g < G_) ? f2bf(w2p[h][(size_t)k*G_ + g]) : (short)0;
      }
      if (tid < H_) sm.b1s[h][tid] = b1p[h][tid];
      if (tid < 16) sm.b2s[h][tid] = (tid < G_) ? b2p[h][tid] : 0.0f;
    }
  }

  __syncthreads();   // weights visible; drains global_load_lds

  float* out_score = out;
  float* out_pi = out + 33;
  float* out_mu = out + 33 + (size_t)TOKS*G_;
  float* out_sg = out + 33 + 2*(size_t)TOKS*G_;
  const float HLOG2PI = 0.91893853320467274f;
  const bool v0 = (q*4+0) < G_, v1 = (q*4+1) < G_, v2 = (q*4+2) < G_, v3 = (q*4+3) < G_;
  const int src_lo = ((q & 1) * 2) * 16 + lg;   // exchange source lanes
  const int src_hi = src_lo + 16;
  const bool qhi = (q >= 2);

  float accP = 0.f, accL = 0.f, accC = 0.f;

  // ---- two 16-token tiles sequentially (small live set; 16 waves hide latency) ----
#pragma unroll
  for (int mt = 0; mt < 2; ++mt) {
    f32x4 lgt[3];
#pragma unroll
    for (int h = 0; h < 3; ++h) {
      // layer 1
      f32x4 acc[8];
#pragma unroll
      for (int nt = 0; nt < 8; ++nt) acc[nt] = (f32x4){0.f,0.f,0.f,0.f};
#pragma unroll
      for (int c = 0; c < 4; ++c) {
#pragma unroll
        for (int nt = 0; nt < 8; ++nt) {
          bf16x8 wfr = *reinterpret_cast<const bf16x8*>(&sm.w1s[h][nt*16 + lg][c*32 + q*8]);
          acc[nt] = __builtin_amdgcn_mfma_f32_16x16x32_bf16(wfr, a1[mt][c], acc[nt], 0, 0, 0);
        }
      }
      // bias+relu+pack: pk[nt] holds hidden[j=nt*16+q*4+{0..3}][tok=lg]
      bf16x4 pk[8];
#pragma unroll
      for (int nt = 0; nt < 8; ++nt) {
        f32x4 b1v = *reinterpret_cast<const f32x4*>(&sm.b1s[h][nt*16 + q*4]);
#pragma unroll
        for (int r = 0; r < 4; ++r)
          pk[nt][r] = f2bf(fmaxf(acc[nt][r] + b1v[r], 0.0f));
      }
      // layer 2: B-frag via in-register exchange.
      // target lane (q,lg) needs hidden[k=c*32+q*8+e][tok=lg]:
      //   lo(e=0..3) from lane src_lo, hi(e=4..7) from lane src_hi,
      //   register pk[2c + (q>>1)] -> two shuffle rounds + select.
      f32x4 lacc = (f32x4){0.f,0.f,0.f,0.f};
#pragma unroll
      for (int c = 0; c < 4; ++c) {
        bf16x4 vA = pk[2*c], vB = pk[2*c+1];
        bf16x4 loA = shfl4(vA, src_lo), hiA = shfl4(vA, src_hi);
        bf16x4 loB = shfl4(vB, src_lo), hiB = shfl4(vB, src_hi);
        bf16x4 lo = qhi ? loB : loA;
        bf16x4 hi = qhi ? hiB : hiA;
        bf16x8 hfr;
        hfr[0]=lo[0]; hfr[1]=lo[1]; hfr[2]=lo[2]; hfr[3]=lo[3];
        hfr[4]=hi[0]; hfr[5]=hi[1]; hfr[6]=hi[2]; hfr[7]=hi[3];
        bf16x8 w2fr = *reinterpret_cast<const bf16x8*>(&sm.w2s[h][lg][c*32 + q*8]);
        lacc = __builtin_amdgcn_mfma_f32_16x16x32_bf16(w2fr, hfr, lacc, 0, 0, 0);
      }
      f32x4 b2v = *reinterpret_cast<const f32x4*>(&sm.b2s[h][q*4]);
      lgt[h] = lacc + b2v;   // row = g = q*4+r, col = token = lg
    }

    // ---- epilogue for this tile ----
    long tok = wtok0 + mt*16 + lg;
    float d  = dpre[mt];
    bool  mk = (mpre[mt] != 0) && (d <= 8.0f);
    f32x4 LP = lgt[0], LS = lgt[1], LM = lgt[2];

    float vm = v0 ? LP[0] : -INFINITY;
    if (v1) vm = fmaxf(vm, LP[1]);
    if (v2) vm = fmaxf(vm, LP[2]);
    if (v3) vm = fmaxf(vm, LP[3]);
    vm = fmaxf(vm, __shfl_xor(vm, 16));
    vm = fmaxf(vm, __shfl_xor(vm, 32));
    float e0 = v0 ? __expf(LP[0]-vm) : 0.f;
    float e1 = v1 ? __expf(LP[1]-vm) : 0.f;
    float e2 = v2 ? __expf(LP[2]-vm) : 0.f;
    float e3 = v3 ? __expf(LP[3]-vm) : 0.f;
    float s = e0+e1+e2+e3;
    s += __shfl_xor(s, 16);
    s += __shfl_xor(s, 32);
    float inv = 1.0f / s;
    float pi[4] = {e0*inv, e1*inv, e2*inv, e3*inv};

    float sg[4], mu[4], ll[4];
#pragma unroll
    for (int r = 0; r < 4; ++r) {
      sg[r] = (LS[r] > 0.f) ? (LS[r] + 1.4f) : (__expf(LS[r]) + 0.4f);
      mu[r] = (LM[r] > 0.f) ? (LM[r] + 1.0f) : __expf(LM[r]);
      float z = (d - mu[r]) / sg[r];
      ll[r] = -0.5f*z*z - __logf(sg[r]) - HLOG2PI;
    }

    if (q*4 < G_) {
      size_t o = (size_t)tok*G_ + q*4;
      *reinterpret_cast<float2*>(&out_pi[o]) = make_float2(pi[0], pi[1]);
      *reinterpret_cast<float2*>(&out_mu[o]) = make_float2(mu[0], mu[1]);
      *reinterpret_cast<float2*>(&out_sg[o]) = make_float2(sg[0], sg[1]);
      if (q*4+2 < G_) {
        *reinterpret_cast<float2*>(&out_pi[o+2]) = make_float2(pi[2], pi[3]);
        *reinterpret_cast<float2*>(&out_mu[o+2]) = make_float2(mu[2], mu[3]);
        *reinterpret_cast<float2*>(&out_sg[o+2]) = make_float2(sg[2], sg[3]);
      }
    }

    float a0 = v0 ? (__logf(pi[0]+1e-10f) + ll[0]) : -INFINITY;
    float a1x= v1 ? (__logf(pi[1]+1e-10f) + ll[1]) : -INFINITY;
    float a2 = v2 ? (__logf(pi[2]+1e-10f) + ll[2]) : -INFINITY;
    float a3 = v3 ? (__logf(pi[3]+1e-10f) + ll[3]) : -INFINITY;
    float m2 = fmaxf(fmaxf(a0,a1x), fmaxf(a2,a3));
    m2 = fmaxf(m2, __shfl_xor(m2, 16));
    m2 = fmaxf(m2, __shfl_xor(m2, 32));
    float s2 = (v0?__expf(a0-m2):0.f) + (v1?__expf(a1x-m2):0.f)
             + (v2?__expf(a2-m2):0.f) + (v3?__expf(a3-m2):0.f);
    s2 += __shfl_xor(s2, 16);
    s2 += __shfl_xor(s2, 32);
    float closs = -(m2 + __logf(s2));

    float s3 = (v0?__expf(ll[0])*pi[0]:0.f) + (v1?__expf(ll[1])*pi[1]:0.f)
             + (v2?__expf(ll[2])*pi[2]:0.f) + (v3?__expf(ll[3])*pi[3]:0.f);
    s3 += __shfl_xor(s3, 16);
    s3 += __shfl_xor(s3, 32);
    float prob = s3 / (d*d + 1e-10f);

    if (lane < 16 && mk) { accP += prob; accL += closs; accC += 1.f; }
  }

  accP += __shfl_xor(accP, 1); accP += __shfl_xor(accP, 2);
  accP += __shfl_xor(accP, 4); accP += __shfl_xor(accP, 8);
  accL += __shfl_xor(accL, 1); accL += __shfl_xor(accL, 2);
  accL += __shfl_xor(accL, 4); accL += __shfl_xor(accL, 8);
  accC += __shfl_xor(accC, 1); accC += __shfl_xor(accC, 2);
  accC += __shfl_xor(accC, 4); accC += __shfl_xor(accC, 8);
  if (lane == 0) { sm.red[wave][0] = accP; sm.red[wave][1] = accL; sm.red[wave][2] = accC; }
  __syncthreads();
  if (tid == 0) {
    float sP = 0.f, sL = 0.f, sC = 0.f;
    for (int w = 0; w < WAVES; ++w) { sP += sm.red[w][0]; sL += sm.red[w][1]; sC += sm.red[w][2]; }
    int b = (int)(((long)blockIdx.x * TPB) >> 13);   // 512 tokens/block, 8192/512=16 blocks per b
    atomicAdd(&out_score[b], sP);
    atomicAdd(&ws[0], sL);
    atomicAdd(&ws[1], sC);
  }
}

extern "C" void kernel_launch(void* const* d_in, const int* in_sizes, int n_in,
                              void* d_out, int out_size, void* d_ws, size_t ws_size,
                              hipStream_t stream) {
  const float* feat = (const float*)d_in[0];
  const float* dist = (const float*)d_in[1];
  const int* dmask = (const int*)d_in[2];
  float* out = (float*)d_out;
  float* ws  = (float*)d_ws;

  hipLaunchKernelGGL(init_kernel, dim3(1), dim3(64), 0, stream, out, ws);

  bool prep_ok = (ws_size >= (size_t)(WS_IMG_OFF + IMG_INSTS*1024));
  if (prep_ok) {
    short* img = (short*)((char*)d_ws + WS_IMG_OFF);
    hipLaunchKernelGGL(prep_kernel, dim3(116), dim3(256), 0, stream,
        (const float*)d_in[3],  (const float*)d_in[4],  (const float*)d_in[5],  (const float*)d_in[6],
        (const float*)d_in[7],  (const float*)d_in[8],  (const float*)d_in[9],  (const float*)d_in[10],
        (const float*)d_in[11], (const float*)d_in[12], (const float*)d_in[13], (const float*)d_in[14],
        img);
    hipLaunchKernelGGL((rtm_main<1>), dim3(TOKS/TPB), dim3(THREADS), 0, stream,
        feat, dist, dmask, (const float*)img,
        (const float*)d_in[3],  (const float*)d_in[4],  (const float*)d_in[5],  (const float*)d_in[6],
        (const float*)d_in[7],  (const float*)d_in[8],  (const float*)d_in[9],  (const float*)d_in[10],
        (const float*)d_in[11], (const float*)d_in[12], (const float*)d_in[13], (const float*)d_in[14],
        out, ws);
  } else {
    hipLaunchKernelGGL((rtm_main<0>), dim3(TOKS/TPB), dim3(THREADS), 0, stream,
        feat, dist, dmask, (const float*)nullptr,
        (const float*)d_in[3],  (const float*)d_in[4],  (const float*)d_in[5],  (const float*)d_in[6],
        (const float*)d_in[7],  (const float*)d_in[8],  (const float*)d_in[9],  (const float*)d_in[10],
        (const float*)d_in[11], (const float*)d_in[12], (const float*)d_in[13], (const float*)d_in[14],
        out, ws);
  }

  hipLaunchKernelGGL(fin_kernel, dim3(1), dim3(64), 0, stream, out, ws);
}

// Round 9
// 96.057 us; speedup vs baseline: 5.4431x; 1.0598x over previous
//
#include <hip/hip_runtime.h>
#include <hip/hip_bf16.h>
#include <math.h>

#define B_   32
#define N_   8192
#define H_   128
#define G_   10
#define TOKS (B_*N_)
#define THREADS 768
#define WAVES 12
#define TPW 32
#define TPB 384   // tokens per block (12 waves x 32)
#define NBLK ((TOKS + TPB - 1) / TPB)   // 683
#define LDW 136   // padded LDS row stride in shorts (272B, 16B-aligned rows)

typedef short bf16x8 __attribute__((ext_vector_type(8)));
typedef short bf16x4 __attribute__((ext_vector_type(4)));
typedef float f32x4 __attribute__((ext_vector_type(4)));

// ws layout: [0..1] loss_sum/mask_count floats; weight image at byte WS_IMG_OFF.
#define WS_IMG_OFF 256
#define IMG_BYTES  119232          // 3*128*136*2 + 3*16*136*2 + 3*128*4 + 3*16*4
#define IMG_INSTS  117             // ceil(IMG_BYTES/1024); overshoot 576B lands in red/pad (safe)

struct __align__(16) SMem {
  // ---- first 119232 bytes == prep image, copied verbatim ----
  short w1s[3][H_][LDW];   // W1^T bf16: [head][hidden j][input i]
  short w2s[3][16][LDW];   // W2^T bf16: [head][g pad16][hidden k]
  float b1s[3][H_];
  float b2s[3][16];
  // ---- scratch (staging overshoot may scribble here pre-barrier; rewritten later) ----
  float red[WAVES][3];
  int   bidx[WAVES];
  char  pad[640];
};

__device__ __forceinline__ short f2bf(float f) {
  __hip_bfloat16 h = __float2bfloat16(f);   // native cvt; compiler fuses pairs into v_cvt_pk_bf16_f32
  union { __hip_bfloat16 h; short s; } u; u.h = h;
  return u.s;
}

__device__ __forceinline__ bf16x4 shfl4(bf16x4 v, int src) {
  union { bf16x4 v; int i[2]; } a, r; a.v = v;
  r.i[0] = __shfl(a.i[0], src, 64);
  r.i[1] = __shfl(a.i[1], src, 64);
  return r.v;
}

__device__ __forceinline__ void async_copy16(void* lds_uniform, const void* gsrc_perlane) {
  __builtin_amdgcn_global_load_lds(
      (const __attribute__((address_space(1))) unsigned int*)gsrc_perlane,
      (__attribute__((address_space(3))) unsigned int*)lds_uniform,
      16, 0, 0);
}

__global__ __launch_bounds__(64) void init_kernel(float* out, float* ws) {
  int t = threadIdx.x;
  if (t < 33) out[t] = 0.0f;
  if (t < 2)  ws[t]  = 0.0f;
}

__global__ __launch_bounds__(64) void fin_kernel(float* out, const float* ws) {
  if (threadIdx.x == 0) out[32] = ws[0] / fmaxf(ws[1], 1.0f);
}

__global__ __launch_bounds__(256) void prep_kernel(
    const float* __restrict__ w1_0, const float* __restrict__ b1_0,
    const float* __restrict__ w2_0, const float* __restrict__ b2_0,
    const float* __restrict__ w1_1, const float* __restrict__ b1_1,
    const float* __restrict__ w2_1, const float* __restrict__ b2_1,
    const float* __restrict__ w1_2, const float* __restrict__ b1_2,
    const float* __restrict__ w2_2, const float* __restrict__ b2_2,
    short* __restrict__ img) {
  const float* w1p[3] = {w1_0, w1_1, w1_2};
  const float* w2p[3] = {w2_0, w2_1, w2_2};
  const float* b1p[3] = {b1_0, b1_1, b1_2};
  const float* b2p[3] = {b2_0, b2_1, b2_2};
  int t = blockIdx.x * 256 + threadIdx.x;
  int stride = gridDim.x * 256;
  for (int idx = t; idx < 3*H_*LDW; idx += stride) {
    int h = idx / (H_*LDW), rem = idx - h*(H_*LDW);
    int j = rem / LDW, i = rem - j*LDW;
    img[idx] = (i < H_) ? f2bf(w1p[h][i*H_ + j]) : (short)0;
  }
  for (int idx = t; idx < 3*16*LDW; idx += stride) {
    int h = idx / (16*LDW), rem = idx - h*(16*LDW);
    int g = rem / LDW, k = rem - g*LDW;
    img[3*H_*LDW + idx] = (g < G_ && k < H_) ? f2bf(w2p[h][k*G_ + g]) : (short)0;
  }
  float* bimg = (float*)(img + 3*H_*LDW + 3*16*LDW);
  if (t < 3*H_ + 3*16) {
    if (t < 3*H_) { int h = t >> 7, j = t & 127; bimg[t] = b1p[h][j]; }
    else { int i2 = t - 3*H_; int h = i2 >> 4, g = i2 & 15;
           bimg[t] = (g < G_) ? b2p[h][g] : 0.0f; }
  }
}

template<int PREP>
__global__ __launch_bounds__(THREADS, 3)   // 170-reg cap: ~100 arch + 64 acc, no spill
void rtm_main(const float* __restrict__ feat,
              const float* __restrict__ dist,
              const int* __restrict__ dmask,
              const float* __restrict__ img,
              const float* __restrict__ w1_0, const float* __restrict__ b1_0,
              const float* __restrict__ w2_0, const float* __restrict__ b2_0,
              const float* __restrict__ w1_1, const float* __restrict__ b1_1,
              const float* __restrict__ w2_1, const float* __restrict__ b2_1,
              const float* __restrict__ w1_2, const float* __restrict__ b1_2,
              const float* __restrict__ w2_2, const float* __restrict__ b2_2,
              float* __restrict__ out, float* __restrict__ ws) {
  __shared__ SMem sm;

  const int tid  = threadIdx.x;
  const int wave = tid >> 6;
  const int lane = tid & 63;
  const int q  = lane >> 4;
  const int lg = lane & 15;
  const long wtok0 = (long)blockIdx.x * TPB + (long)wave * TPW;
  const bool active = (wtok0 < TOKS);   // tail block: waves 8..11 idle

  // ---- token scalars + feature fragments for both tiles (pre-barrier) ----
  float dpre[2]; int mpre[2];
  bf16x8 a1[2][4];   // B-frag: lane holds B[k=(lane>>4)*8+e][tok=lane&15]
  if (active) {
#pragma unroll
    for (int mt = 0; mt < 2; ++mt) {
      long tok = wtok0 + mt*16 + lg;
      dpre[mt] = dist[tok];
      mpre[mt] = dmask[tok];
    }
#pragma unroll
    for (int mt = 0; mt < 2; ++mt) {
      const float* fr = feat + (wtok0 + mt*16 + lg) * (long)H_;
#pragma unroll
      for (int c = 0; c < 4; ++c) {
        const float4* p = reinterpret_cast<const float4*>(fr + c*32 + q*8);
        float4 lo = p[0], hi = p[1];
        bf16x8 a;
        a[0]=f2bf(lo.x); a[1]=f2bf(lo.y); a[2]=f2bf(lo.z); a[3]=f2bf(lo.w);
        a[4]=f2bf(hi.x); a[5]=f2bf(hi.y); a[6]=f2bf(hi.z); a[7]=f2bf(hi.w);
        a1[mt][c] = a;
      }
    }
  }

  // ---- stage weight image to LDS (async, once per block) ----
  if constexpr (PREP) {
    char* smb = (char*)&sm;
    const char* gimg = (const char*)img;
    for (int i = wave; i < IMG_INSTS; i += WAVES)
      async_copy16(smb + i*1024, gimg + i*1024 + lane*16);
  } else {
    const float* w1p[3] = {w1_0, w1_1, w1_2};
    const float* w2p[3] = {w2_0, w2_1, w2_2};
    const float* b1p[3] = {b1_0, b1_1, b1_2};
    const float* b2p[3] = {b2_0, b2_1, b2_2};
    for (int h = 0; h < 3; ++h) {
      for (int idx = tid; idx < H_*H_; idx += THREADS) {
        int i = idx >> 7, j = idx & 127;
        sm.w1s[h][j][i] = f2bf(w1p[h][idx]);
      }
      for (int idx = tid; idx < 16*H_; idx += THREADS) {
        int g = idx >> 7, k = idx & 127;
        sm.w2s[h][g][k] = (g < G_) ? f2bf(w2p[h][(size_t)k*G_ + g]) : (short)0;
      }
      if (tid < H_) sm.b1s[h][tid] = b1p[h][tid];
      if (tid < 16) sm.b2s[h][tid] = (tid < G_) ? b2p[h][tid] : 0.0f;
    }
  }

  __syncthreads();   // weights visible; drains global_load_lds

  float* out_score = out;
  float* out_pi = out + 33;
  float* out_mu = out + 33 + (size_t)TOKS*G_;
  float* out_sg = out + 33 + 2*(size_t)TOKS*G_;
  const float HLOG2PI = 0.91893853320467274f;
  const bool v0 = (q*4+0) < G_, v1 = (q*4+1) < G_, v2 = (q*4+2) < G_, v3 = (q*4+3) < G_;
  const int src_lo = ((q & 1) * 2) * 16 + lg;   // exchange source lanes
  const int src_hi = src_lo + 16;
  const bool qhi = (q >= 2);

  float accP = 0.f, accL = 0.f, accC = 0.f;

  if (active) {
    f32x4 lgt[3][2];
#pragma unroll
    for (int h = 0; h < 3; ++h) {
      // ---- layer 1: W1 fragment read ONCE feeds both M-tiles ----
      f32x4 acc[2][8];
#pragma unroll
      for (int mt = 0; mt < 2; ++mt)
#pragma unroll
        for (int nt = 0; nt < 8; ++nt) acc[mt][nt] = (f32x4){0.f,0.f,0.f,0.f};
#pragma unroll
      for (int c = 0; c < 4; ++c) {
#pragma unroll
        for (int nt = 0; nt < 8; ++nt) {
          bf16x8 wfr = *reinterpret_cast<const bf16x8*>(&sm.w1s[h][nt*16 + lg][c*32 + q*8]);
          acc[0][nt] = __builtin_amdgcn_mfma_f32_16x16x32_bf16(wfr, a1[0][c], acc[0][nt], 0, 0, 0);
          acc[1][nt] = __builtin_amdgcn_mfma_f32_16x16x32_bf16(wfr, a1[1][c], acc[1][nt], 0, 0, 0);
        }
      }
#pragma unroll
      for (int mt = 0; mt < 2; ++mt) {
        // bias+relu+pack: pk[nt] holds hidden[j=nt*16+q*4+{0..3}][tok=lg]
        bf16x4 pk[8];
#pragma unroll
        for (int nt = 0; nt < 8; ++nt) {
          f32x4 b1v = *reinterpret_cast<const f32x4*>(&sm.b1s[h][nt*16 + q*4]);
#pragma unroll
          for (int r = 0; r < 4; ++r)
            pk[nt][r] = f2bf(fmaxf(acc[mt][nt][r] + b1v[r], 0.0f));
        }
        // layer 2: B-frag via in-register exchange (validated round 8).
        f32x4 lacc = (f32x4){0.f,0.f,0.f,0.f};
#pragma unroll
        for (int c = 0; c < 4; ++c) {
          bf16x4 vA = pk[2*c], vB = pk[2*c+1];
          bf16x4 loA = shfl4(vA, src_lo), hiA = shfl4(vA, src_hi);
          bf16x4 loB = shfl4(vB, src_lo), hiB = shfl4(vB, src_hi);
          bf16x4 lo = qhi ? loB : loA;
          bf16x4 hi = qhi ? hiB : hiA;
          bf16x8 hfr;
          hfr[0]=lo[0]; hfr[1]=lo[1]; hfr[2]=lo[2]; hfr[3]=lo[3];
          hfr[4]=hi[0]; hfr[5]=hi[1]; hfr[6]=hi[2]; hfr[7]=hi[3];
          bf16x8 w2fr = *reinterpret_cast<const bf16x8*>(&sm.w2s[h][lg][c*32 + q*8]);
          lacc = __builtin_amdgcn_mfma_f32_16x16x32_bf16(w2fr, hfr, lacc, 0, 0, 0);
        }
        f32x4 b2v = *reinterpret_cast<const f32x4*>(&sm.b2s[h][q*4]);
        lgt[h][mt] = lacc + b2v;   // row = g = q*4+r, col = token = lg
      }
    }

    // ---- epilogue ----
#pragma unroll
    for (int mt = 0; mt < 2; ++mt) {
      long tok = wtok0 + mt*16 + lg;
      float d  = dpre[mt];
      bool  mk = (mpre[mt] != 0) && (d <= 8.0f);
      f32x4 LP = lgt[0][mt], LS = lgt[1][mt], LM = lgt[2][mt];

      float vm = v0 ? LP[0] : -INFINITY;
      if (v1) vm = fmaxf(vm, LP[1]);
      if (v2) vm = fmaxf(vm, LP[2]);
      if (v3) vm = fmaxf(vm, LP[3]);
      vm = fmaxf(vm, __shfl_xor(vm, 16));
      vm = fmaxf(vm, __shfl_xor(vm, 32));
      float e0 = v0 ? __expf(LP[0]-vm) : 0.f;
      float e1 = v1 ? __expf(LP[1]-vm) : 0.f;
      float e2 = v2 ? __expf(LP[2]-vm) : 0.f;
      float e3 = v3 ? __expf(LP[3]-vm) : 0.f;
      float s = e0+e1+e2+e3;
      s += __shfl_xor(s, 16);
      s += __shfl_xor(s, 32);
      float inv = 1.0f / s;
      float pi[4] = {e0*inv, e1*inv, e2*inv, e3*inv};

      float sg[4], mu[4], ll[4];
#pragma unroll
      for (int r = 0; r < 4; ++r) {
        sg[r] = (LS[r] > 0.f) ? (LS[r] + 1.4f) : (__expf(LS[r]) + 0.4f);
        mu[r] = (LM[r] > 0.f) ? (LM[r] + 1.0f) : __expf(LM[r]);
        float z = (d - mu[r]) / sg[r];
        ll[r] = -0.5f*z*z - __logf(sg[r]) - HLOG2PI;
      }

      if (q*4 < G_) {
        size_t o = (size_t)tok*G_ + q*4;
        *reinterpret_cast<float2*>(&out_pi[o]) = make_float2(pi[0], pi[1]);
        *reinterpret_cast<float2*>(&out_mu[o]) = make_float2(mu[0], mu[1]);
        *reinterpret_cast<float2*>(&out_sg[o]) = make_float2(sg[0], sg[1]);
        if (q*4+2 < G_) {
          *reinterpret_cast<float2*>(&out_pi[o+2]) = make_float2(pi[2], pi[3]);
          *reinterpret_cast<float2*>(&out_mu[o+2]) = make_float2(mu[2], mu[3]);
          *reinterpret_cast<float2*>(&out_sg[o+2]) = make_float2(sg[2], sg[3]);
        }
      }

      float a0 = v0 ? (__logf(pi[0]+1e-10f) + ll[0]) : -INFINITY;
      float a1x= v1 ? (__logf(pi[1]+1e-10f) + ll[1]) : -INFINITY;
      float a2 = v2 ? (__logf(pi[2]+1e-10f) + ll[2]) : -INFINITY;
      float a3 = v3 ? (__logf(pi[3]+1e-10f) + ll[3]) : -INFINITY;
      float m2 = fmaxf(fmaxf(a0,a1x), fmaxf(a2,a3));
      m2 = fmaxf(m2, __shfl_xor(m2, 16));
      m2 = fmaxf(m2, __shfl_xor(m2, 32));
      float s2 = (v0?__expf(a0-m2):0.f) + (v1?__expf(a1x-m2):0.f)
               + (v2?__expf(a2-m2):0.f) + (v3?__expf(a3-m2):0.f);
      s2 += __shfl_xor(s2, 16);
      s2 += __shfl_xor(s2, 32);
      float closs = -(m2 + __logf(s2));

      float s3 = (v0?__expf(ll[0])*pi[0]:0.f) + (v1?__expf(ll[1])*pi[1]:0.f)
               + (v2?__expf(ll[2])*pi[2]:0.f) + (v3?__expf(ll[3])*pi[3]:0.f);
      s3 += __shfl_xor(s3, 16);
      s3 += __shfl_xor(s3, 32);
      float prob = s3 / (d*d + 1e-10f);

      if (lane < 16 && mk) { accP += prob; accL += closs; accC += 1.f; }
    }
  }

  accP += __shfl_xor(accP, 1); accP += __shfl_xor(accP, 2);
  accP += __shfl_xor(accP, 4); accP += __shfl_xor(accP, 8);
  accL += __shfl_xor(accL, 1); accL += __shfl_xor(accL, 2);
  accL += __shfl_xor(accL, 4); accL += __shfl_xor(accL, 8);
  accC += __shfl_xor(accC, 1); accC += __shfl_xor(accC, 2);
  accC += __shfl_xor(accC, 4); accC += __shfl_xor(accC, 8);
  if (lane == 0) {
    sm.red[wave][0] = accP; sm.red[wave][1] = accL; sm.red[wave][2] = accC;
    sm.bidx[wave] = active ? (int)(wtok0 >> 13) : 0;   // batch idx; uniform per wave
  }
  __syncthreads();
  if (tid == 0) {
    // block may straddle one batch boundary -> at most 2 distinct b among waves
    float sP0 = 0.f, sP1 = 0.f, sL = 0.f, sC = 0.f;
    int b0 = sm.bidx[0], b1 = -1;
    for (int w = 0; w < WAVES; ++w) {
      sL += sm.red[w][1]; sC += sm.red[w][2];
      if (sm.bidx[w] == b0) sP0 += sm.red[w][0];
      else { b1 = sm.bidx[w]; sP1 += sm.red[w][0]; }
    }
    atomicAdd(&out_score[b0], sP0);
    if (b1 >= 0) atomicAdd(&out_score[b1], sP1);
    atomicAdd(&ws[0], sL);
    atomicAdd(&ws[1], sC);
  }
}

extern "C" void kernel_launch(void* const* d_in, const int* in_sizes, int n_in,
                              void* d_out, int out_size, void* d_ws, size_t ws_size,
                              hipStream_t stream) {
  const float* feat = (const float*)d_in[0];
  const float* dist = (const float*)d_in[1];
  const int* dmask = (const int*)d_in[2];
  float* out = (float*)d_out;
  float* ws  = (float*)d_ws;

  hipLaunchKernelGGL(init_kernel, dim3(1), dim3(64), 0, stream, out, ws);

  bool prep_ok = (ws_size >= (size_t)(WS_IMG_OFF + IMG_INSTS*1024));
  if (prep_ok) {
    short* img = (short*)((char*)d_ws + WS_IMG_OFF);
    hipLaunchKernelGGL(prep_kernel, dim3(116), dim3(256), 0, stream,
        (const float*)d_in[3],  (const float*)d_in[4],  (const float*)d_in[5],  (const float*)d_in[6],
        (const float*)d_in[7],  (const float*)d_in[8],  (const float*)d_in[9],  (const float*)d_in[10],
        (const float*)d_in[11], (const float*)d_in[12], (const float*)d_in[13], (const float*)d_in[14],
        img);
    hipLaunchKernelGGL((rtm_main<1>), dim3(NBLK), dim3(THREADS), 0, stream,
        feat, dist, dmask, (const float*)img,
        (const float*)d_in[3],  (const float*)d_in[4],  (const float*)d_in[5],  (const float*)d_in[6],
        (const float*)d_in[7],  (const float*)d_in[8],  (const float*)d_in[9],  (const float*)d_in[10],
        (const float*)d_in[11], (const float*)d_in[12], (const float*)d_in[13], (const float*)d_in[14],
        out, ws);
  } else {
    hipLaunchKernelGGL((rtm_main<0>), dim3(NBLK), dim3(THREADS), 0, stream,
        feat, dist, dmask, (const float*)nullptr,
        (const float*)d_in[3],  (const float*)d_in[4],  (const float*)d_in[5],  (const float*)d_in[6],
        (const float*)d_in[7],  (const float*)d_in[8],  (const float*)d_in[9],  (const float*)d_in[10],
        (const float*)d_in[11], (const float*)d_in[12], (const float*)d_in[13], (const float*)d_in[14],
        out, ws);
  }

  hipLaunchKernelGGL(fin_kernel, dim3(1), dim3(64), 0, stream, out, ws);
}

// Round 11
// 72.387 us; speedup vs baseline: 7.2229x; 1.3270x over previous
//
#include <hip/hip_runtime.h>
#include <hip/hip_bf16.h>
#include <math.h>

#define B_   32
#define N_   8192
#define H_   128
#define G_   10
#define TOKS (B_*N_)
#define THREADS 512
#define WAVES 8
#define NITER 4
#define TPB 1024   // 8 waves x 32 tok/tile x 4 tiles -> grid = exactly 256 blocks (1/CU)
#define LDW 136    // padded LDS row stride in shorts (272B, 16B-aligned rows)

typedef short bf16x8 __attribute__((ext_vector_type(8)));
typedef short bf16x4 __attribute__((ext_vector_type(4)));
typedef float f32x4 __attribute__((ext_vector_type(4)));

// ws layout: [0..1] loss_sum/mask_count floats; weight image at byte WS_IMG_OFF.
#define WS_IMG_OFF 256
#define IMG_BYTES  119232          // 3*128*136*2 + 3*16*136*2 + 3*128*4 + 3*16*4
#define IMG_INSTS  117             // ceil(IMG_BYTES/1024); overshoot 576B lands in red/pad (safe)

struct __align__(16) SMem {
  // ---- first 119232 bytes == prep image, copied verbatim ----
  short w1s[3][H_][LDW];   // W1^T bf16: [head][hidden j][input i]
  short w2s[3][16][LDW];   // W2^T bf16: [head][g pad16][hidden k]
  float b1s[3][H_];
  float b2s[3][16];
  // ---- scratch (staging overshoot scribbles here pre-barrier; rewritten later) ----
  float red[WAVES][3];
  char  pad[512];
};

__device__ __forceinline__ short f2bf(float f) {
  __hip_bfloat16 h = __float2bfloat16(f);
  union { __hip_bfloat16 h; short s; } u; u.h = h;
  return u.s;
}

__device__ __forceinline__ bf16x4 shfl4(bf16x4 v, int src) {
  union { bf16x4 v; int i[2]; } a, r; a.v = v;
  r.i[0] = __shfl(a.i[0], src, 64);
  r.i[1] = __shfl(a.i[1], src, 64);
  return r.v;
}

__device__ __forceinline__ void async_copy16(void* lds_uniform, const void* gsrc_perlane) {
  __builtin_amdgcn_global_load_lds(
      (const __attribute__((address_space(1))) unsigned int*)gsrc_perlane,
      (__attribute__((address_space(3))) unsigned int*)lds_uniform,
      16, 0, 0);
}

__global__ __launch_bounds__(64) void init_kernel(float* out, float* ws) {
  int t = threadIdx.x;
  if (t < 33) out[t] = 0.0f;
  if (t < 2)  ws[t]  = 0.0f;
}

__global__ __launch_bounds__(64) void fin_kernel(float* out, const float* ws) {
  if (threadIdx.x == 0) out[32] = ws[0] / fmaxf(ws[1], 1.0f);
}

__global__ __launch_bounds__(256) void prep_kernel(
    const float* __restrict__ w1_0, const float* __restrict__ b1_0,
    const float* __restrict__ w2_0, const float* __restrict__ b2_0,
    const float* __restrict__ w1_1, const float* __restrict__ b1_1,
    const float* __restrict__ w2_1, const float* __restrict__ b2_1,
    const float* __restrict__ w1_2, const float* __restrict__ b1_2,
    const float* __restrict__ w2_2, const float* __restrict__ b2_2,
    short* __restrict__ img) {
  const float* w1p[3] = {w1_0, w1_1, w1_2};
  const float* w2p[3] = {w2_0, w2_1, w2_2};
  const float* b1p[3] = {b1_0, b1_1, b1_2};
  const float* b2p[3] = {b2_0, b2_1, b2_2};
  int t = blockIdx.x * 256 + threadIdx.x;
  int stride = gridDim.x * 256;
  for (int idx = t; idx < 3*H_*LDW; idx += stride) {
    int h = idx / (H_*LDW), rem = idx - h*(H_*LDW);
    int j = rem / LDW, i = rem - j*LDW;
    img[idx] = (i < H_) ? f2bf(w1p[h][i*H_ + j]) : (short)0;
  }
  for (int idx = t; idx < 3*16*LDW; idx += stride) {
    int h = idx / (16*LDW), rem = idx - h*(16*LDW);
    int g = rem / LDW, k = rem - g*LDW;
    img[3*H_*LDW + idx] = (g < G_ && k < H_) ? f2bf(w2p[h][k*G_ + g]) : (short)0;
  }
  float* bimg = (float*)(img + 3*H_*LDW + 3*16*LDW);
  if (t < 3*H_ + 3*16) {
    if (t < 3*H_) { int h = t >> 7, j = t & 127; bimg[t] = b1p[h][j]; }
    else { int i2 = t - 3*H_; int h = i2 >> 4, g = i2 & 15;
           bimg[t] = (g < G_) ? b2p[h][g] : 0.0f; }
  }
}

template<int PREP>
__global__ __launch_bounds__(THREADS, 2)   // 256-reg cap; est ~225 live, no spill
void rtm_main(const float* __restrict__ feat,
              const float* __restrict__ dist,
              const int* __restrict__ dmask,
              const float* __restrict__ img,
              const float* __restrict__ w1_0, const float* __restrict__ b1_0,
              const float* __restrict__ w2_0, const float* __restrict__ b2_0,
              const float* __restrict__ w1_1, const float* __restrict__ b1_1,
              const float* __restrict__ w2_1, const float* __restrict__ b2_1,
              const float* __restrict__ w1_2, const float* __restrict__ b1_2,
              const float* __restrict__ w2_2, const float* __restrict__ b2_2,
              float* __restrict__ out, float* __restrict__ ws) {
  __shared__ SMem sm;

  const int tid  = threadIdx.x;
  const int wave = tid >> 6;
  const int lane = tid & 63;
  const int q  = lane >> 4;
  const int lg = lane & 15;
  // wave owns 128 contiguous tokens: 4 tiles x (2 sub-tiles x 16 tokens)
  const long wbase = (long)blockIdx.x * TPB + (long)wave * (32*NITER);

  // ---- prologue: issue tile-0 loads (both 16-token sub-tiles) ----
  float4 fv[2][8];
  float dpre[2]; int mpre[2];
#pragma unroll
  for (int mt = 0; mt < 2; ++mt) {
    const float* fr = feat + (wbase + mt*16 + lg) * (long)H_;
#pragma unroll
    for (int c = 0; c < 4; ++c) {
      const float4* p = reinterpret_cast<const float4*>(fr + c*32 + q*8);
      fv[mt][2*c]   = p[0];
      fv[mt][2*c+1] = p[1];
    }
    dpre[mt] = dist[wbase + mt*16 + lg];
    mpre[mt] = dmask[wbase + mt*16 + lg];
  }

  // ---- stage weight image to LDS (async; once per CU) ----
  if constexpr (PREP) {
    char* smb = (char*)&sm;
    const char* gimg = (const char*)img;
    for (int i = wave; i < IMG_INSTS; i += WAVES)
      async_copy16(smb + i*1024, gimg + i*1024 + lane*16);
  } else {
    const float* w1p[3] = {w1_0, w1_1, w1_2};
    const float* w2p[3] = {w2_0, w2_1, w2_2};
    const float* b1p[3] = {b1_0, b1_1, b1_2};
    const float* b2p[3] = {b2_0, b2_1, b2_2};
    for (int h = 0; h < 3; ++h) {
      for (int idx = tid; idx < H_*H_; idx += THREADS) {
        int i = idx >> 7, j = idx & 127;
        sm.w1s[h][j][i] = f2bf(w1p[h][idx]);
      }
      for (int idx = tid; idx < 16*H_; idx += THREADS) {
        int g = idx >> 7, k = idx & 127;
        sm.w2s[h][g][k] = (g < G_) ? f2bf(w2p[h][(size_t)k*G_ + g]) : (short)0;
      }
      if (tid < H_) sm.b1s[h][tid] = b1p[h][tid];
      if (tid < 16) sm.b2s[h][tid] = (tid < G_) ? b2p[h][tid] : 0.0f;
    }
  }

  // ---- convert tile 0 while staging is in flight ----
  bf16x8 a1[2][4];   // B-frag: lane holds B[k=(lane>>4)*8+e][tok=lane&15]
#pragma unroll
  for (int mt = 0; mt < 2; ++mt)
#pragma unroll
    for (int c = 0; c < 4; ++c) {
      float4 lo = fv[mt][2*c], hi = fv[mt][2*c+1];
      bf16x8 a;
      a[0]=f2bf(lo.x); a[1]=f2bf(lo.y); a[2]=f2bf(lo.z); a[3]=f2bf(lo.w);
      a[4]=f2bf(hi.x); a[5]=f2bf(hi.y); a[6]=f2bf(hi.z); a[7]=f2bf(hi.w);
      a1[mt][c] = a;
    }

  __syncthreads();   // weights visible; drains global_load_lds

  float* out_score = out;
  float* out_pi = out + 33;
  float* out_mu = out + 33 + (size_t)TOKS*G_;
  float* out_sg = out + 33 + 2*(size_t)TOKS*G_;
  const float HLOG2PI = 0.91893853320467274f;
  const bool v0 = (q*4+0) < G_, v1 = (q*4+1) < G_, v2 = (q*4+2) < G_, v3 = (q*4+3) < G_;
  const int src_lo = ((q & 1) * 2) * 16 + lg;
  const int src_hi = src_lo + 16;
  const bool qhi = (q >= 2);

  float accP = 0.f, accL = 0.f, accC = 0.f;

  // ---- pipelined tile loop: loads(s+1) fire under compute(s) ----
#pragma unroll
  for (int s = 0; s < NITER; ++s) {
    float dnx[2]; int mnx[2];
    if (s + 1 < NITER) {   // issue next tile's loads (fv drained by last convert)
#pragma unroll
      for (int mt = 0; mt < 2; ++mt) {
        const float* fr = feat + (wbase + (s+1)*32 + mt*16 + lg) * (long)H_;
#pragma unroll
        for (int c = 0; c < 4; ++c) {
          const float4* p = reinterpret_cast<const float4*>(fr + c*32 + q*8);
          fv[mt][2*c]   = p[0];
          fv[mt][2*c+1] = p[1];
        }
        dnx[mt] = dist[wbase + (s+1)*32 + mt*16 + lg];
        mnx[mt] = dmask[wbase + (s+1)*32 + mt*16 + lg];
      }
    }

    // ---- compute tile s: two sub-tiles share each W1 fragment (r9 body) ----
    f32x4 lgt[3][2];
#pragma unroll
    for (int h = 0; h < 3; ++h) {
      f32x4 acc[2][8];
#pragma unroll
      for (int mt = 0; mt < 2; ++mt)
#pragma unroll
        for (int nt = 0; nt < 8; ++nt) acc[mt][nt] = (f32x4){0.f,0.f,0.f,0.f};
#pragma unroll
      for (int c = 0; c < 4; ++c) {
#pragma unroll
        for (int nt = 0; nt < 8; ++nt) {
          bf16x8 wfr = *reinterpret_cast<const bf16x8*>(&sm.w1s[h][nt*16 + lg][c*32 + q*8]);
          acc[0][nt] = __builtin_amdgcn_mfma_f32_16x16x32_bf16(wfr, a1[0][c], acc[0][nt], 0, 0, 0);
          acc[1][nt] = __builtin_amdgcn_mfma_f32_16x16x32_bf16(wfr, a1[1][c], acc[1][nt], 0, 0, 0);
        }
      }
#pragma unroll
      for (int mt = 0; mt < 2; ++mt) {
        bf16x4 pk[8];
#pragma unroll
        for (int nt = 0; nt < 8; ++nt) {
          f32x4 b1v = *reinterpret_cast<const f32x4*>(&sm.b1s[h][nt*16 + q*4]);
#pragma unroll
          for (int r = 0; r < 4; ++r)
            pk[nt][r] = f2bf(fmaxf(acc[mt][nt][r] + b1v[r], 0.0f));
        }
        f32x4 lacc = (f32x4){0.f,0.f,0.f,0.f};
#pragma unroll
        for (int c = 0; c < 4; ++c) {
          bf16x4 vA = pk[2*c], vB = pk[2*c+1];
          bf16x4 loA = shfl4(vA, src_lo), hiA = shfl4(vA, src_hi);
          bf16x4 loB = shfl4(vB, src_lo), hiB = shfl4(vB, src_hi);
          bf16x4 lo = qhi ? loB : loA;
          bf16x4 hi = qhi ? hiB : hiA;
          bf16x8 hfr;
          hfr[0]=lo[0]; hfr[1]=lo[1]; hfr[2]=lo[2]; hfr[3]=lo[3];
          hfr[4]=hi[0]; hfr[5]=hi[1]; hfr[6]=hi[2]; hfr[7]=hi[3];
          bf16x8 w2fr = *reinterpret_cast<const bf16x8*>(&sm.w2s[h][lg][c*32 + q*8]);
          lacc = __builtin_amdgcn_mfma_f32_16x16x32_bf16(w2fr, hfr, lacc, 0, 0, 0);
        }
        f32x4 b2v = *reinterpret_cast<const f32x4*>(&sm.b2s[h][q*4]);
        lgt[h][mt] = lacc + b2v;   // row = g = q*4+r, col = token = lg
      }
    }

    // ---- epilogue tile s (both sub-tiles) ----
#pragma unroll
    for (int mt = 0; mt < 2; ++mt) {
      long tok = wbase + s*32 + mt*16 + lg;
      float d  = dpre[mt];
      bool  mk = (mpre[mt] != 0) && (d <= 8.0f);
      f32x4 LP = lgt[0][mt], LS = lgt[1][mt], LM = lgt[2][mt];

      float vm = v0 ? LP[0] : -INFINITY;
      if (v1) vm = fmaxf(vm, LP[1]);
      if (v2) vm = fmaxf(vm, LP[2]);
      if (v3) vm = fmaxf(vm, LP[3]);
      vm = fmaxf(vm, __shfl_xor(vm, 16));
      vm = fmaxf(vm, __shfl_xor(vm, 32));
      float e0 = v0 ? __expf(LP[0]-vm) : 0.f;
      float e1 = v1 ? __expf(LP[1]-vm) : 0.f;
      float e2 = v2 ? __expf(LP[2]-vm) : 0.f;
      float e3 = v3 ? __expf(LP[3]-vm) : 0.f;
      float ssum = e0+e1+e2+e3;
      ssum += __shfl_xor(ssum, 16);
      ssum += __shfl_xor(ssum, 32);
      float inv = 1.0f / ssum;
      float pi[4] = {e0*inv, e1*inv, e2*inv, e3*inv};

      float sg[4], mu[4], ll[4];
#pragma unroll
      for (int r = 0; r < 4; ++r) {
        sg[r] = (LS[r] > 0.f) ? (LS[r] + 1.4f) : (__expf(LS[r]) + 0.4f);
        mu[r] = (LM[r] > 0.f) ? (LM[r] + 1.0f) : __expf(LM[r]);
        float z = (d - mu[r]) / sg[r];
        ll[r] = -0.5f*z*z - __logf(sg[r]) - HLOG2PI;
      }

      if (q*4 < G_) {
        size_t o = (size_t)tok*G_ + q*4;
        *reinterpret_cast<float2*>(&out_pi[o]) = make_float2(pi[0], pi[1]);
        *reinterpret_cast<float2*>(&out_mu[o]) = make_float2(mu[0], mu[1]);
        *reinterpret_cast<float2*>(&out_sg[o]) = make_float2(sg[0], sg[1]);
        if (q*4+2 < G_) {
          *reinterpret_cast<float2*>(&out_pi[o+2]) = make_float2(pi[2], pi[3]);
          *reinterpret_cast<float2*>(&out_mu[o+2]) = make_float2(mu[2], mu[3]);
          *reinterpret_cast<float2*>(&out_sg[o+2]) = make_float2(sg[2], sg[3]);
        }
      }

      float a0 = v0 ? (__logf(pi[0]+1e-10f) + ll[0]) : -INFINITY;
      float a1x= v1 ? (__logf(pi[1]+1e-10f) + ll[1]) : -INFINITY;
      float a2 = v2 ? (__logf(pi[2]+1e-10f) + ll[2]) : -INFINITY;
      float a3 = v3 ? (__logf(pi[3]+1e-10f) + ll[3]) : -INFINITY;
      float m2 = fmaxf(fmaxf(a0,a1x), fmaxf(a2,a3));
      m2 = fmaxf(m2, __shfl_xor(m2, 16));
      m2 = fmaxf(m2, __shfl_xor(m2, 32));
      float s2 = (v0?__expf(a0-m2):0.f) + (v1?__expf(a1x-m2):0.f)
               + (v2?__expf(a2-m2):0.f) + (v3?__expf(a3-m2):0.f);
      s2 += __shfl_xor(s2, 16);
      s2 += __shfl_xor(s2, 32);
      float closs = -(m2 + __logf(s2));

      float s3 = (v0?__expf(ll[0])*pi[0]:0.f) + (v1?__expf(ll[1])*pi[1]:0.f)
               + (v2?__expf(ll[2])*pi[2]:0.f) + (v3?__expf(ll[3])*pi[3]:0.f);
      s3 += __shfl_xor(s3, 16);
      s3 += __shfl_xor(s3, 32);
      float prob = s3 / (d*d + 1e-10f);

      if (lane < 16 && mk) { accP += prob; accL += closs; accC += 1.f; }
    }

    // ---- convert next tile (loads had the whole compute+epilogue to land) ----
    if (s + 1 < NITER) {
#pragma unroll
      for (int mt = 0; mt < 2; ++mt) {
#pragma unroll
        for (int c = 0; c < 4; ++c) {
          float4 lo = fv[mt][2*c], hi = fv[mt][2*c+1];
          bf16x8 a;
          a[0]=f2bf(lo.x); a[1]=f2bf(lo.y); a[2]=f2bf(lo.z); a[3]=f2bf(lo.w);
          a[4]=f2bf(hi.x); a[5]=f2bf(hi.y); a[6]=f2bf(hi.z); a[7]=f2bf(hi.w);
          a1[mt][c] = a;
        }
        dpre[mt] = dnx[mt]; mpre[mt] = mnx[mt];
      }
    }
  }

  // ---- block reduce; block lies entirely in one batch b ----
  accP += __shfl_xor(accP, 1); accP += __shfl_xor(accP, 2);
  accP += __shfl_xor(accP, 4); accP += __shfl_xor(accP, 8);
  accL += __shfl_xor(accL, 1); accL += __shfl_xor(accL, 2);
  accL += __shfl_xor(accL, 4); accL += __shfl_xor(accL, 8);
  accC += __shfl_xor(accC, 1); accC += __shfl_xor(accC, 2);
  accC += __shfl_xor(accC, 4); accC += __shfl_xor(accC, 8);
  if (lane == 0) { sm.red[wave][0] = accP; sm.red[wave][1] = accL; sm.red[wave][2] = accC; }
  __syncthreads();
  if (tid == 0) {
    float sP = 0.f, sL = 0.f, sC = 0.f;
    for (int w = 0; w < WAVES; ++w) { sP += sm.red[w][0]; sL += sm.red[w][1]; sC += sm.red[w][2]; }
    int b = blockIdx.x >> 3;   // 8 blocks per batch (1024 tokens/block)
    atomicAdd(&out_score[b], sP);
    atomicAdd(&ws[0], sL);
    atomicAdd(&ws[1], sC);
  }
}

extern "C" void kernel_launch(void* const* d_in, const int* in_sizes, int n_in,
                              void* d_out, int out_size, void* d_ws, size_t ws_size,
                              hipStream_t stream) {
  const float* feat = (const float*)d_in[0];
  const float* dist = (const float*)d_in[1];
  const int* dmask = (const int*)d_in[2];
  float* out = (float*)d_out;
  float* ws  = (float*)d_ws;

  hipLaunchKernelGGL(init_kernel, dim3(1), dim3(64), 0, stream, out, ws);

  bool prep_ok = (ws_size >= (size_t)(WS_IMG_OFF + IMG_INSTS*1024));
  if (prep_ok) {
    short* img = (short*)((char*)d_ws + WS_IMG_OFF);
    hipLaunchKernelGGL(prep_kernel, dim3(116), dim3(256), 0, stream,
        (const float*)d_in[3],  (const float*)d_in[4],  (const float*)d_in[5],  (const float*)d_in[6],
        (const float*)d_in[7],  (const float*)d_in[8],  (const float*)d_in[9],  (const float*)d_in[10],
        (const float*)d_in[11], (const float*)d_in[12], (const float*)d_in[13], (const float*)d_in[14],
        img);
    hipLaunchKernelGGL((rtm_main<1>), dim3(TOKS/TPB), dim3(THREADS), 0, stream,
        feat, dist, dmask, (const float*)img,
        (const float*)d_in[3],  (const float*)d_in[4],  (const float*)d_in[5],  (const float*)d_in[6],
        (const float*)d_in[7],  (const float*)d_in[8],  (const float*)d_in[9],  (const float*)d_in[10],
        (const float*)d_in[11], (const float*)d_in[12], (const float*)d_in[13], (const float*)d_in[14],
        out, ws);
  } else {
    hipLaunchKernelGGL((rtm_main<0>), dim3(TOKS/TPB), dim3(THREADS), 0, stream,
        feat, dist, dmask, (const float*)nullptr,
        (const float*)d_in[3],  (const float*)d_in[4],  (const float*)d_in[5],  (const float*)d_in[6],
        (const float*)d_in[7],  (const float*)d_in[8],  (const float*)d_in[9],  (const float*)d_in[10],
        (const float*)d_in[11], (const float*)d_in[12], (const float*)d_in[13], (const float*)d_in[14],
        out, ws);
  }

  hipLaunchKernelGGL(fin_kernel, dim3(1), dim3(64), 0, stream, out, ws);
}

// Round 12
// 68.802 us; speedup vs baseline: 7.5993x; 1.0521x over previous
//
#include <hip/hip_runtime.h>
#include <hip/hip_bf16.h>
#include <math.h>

#define B_   32
#define N_   8192
#define H_   128
#define G_   10
#define TOKS (B_*N_)
#define THREADS 512
#define WAVES 8
#define NITER 4
#define TPB 1024   // 8 waves x 32 tok/tile x 4 tiles -> grid = exactly 256 blocks (1/CU)
#define LDW 136    // padded LDS row stride in shorts (272B, 16B-aligned rows)

typedef short bf16x8 __attribute__((ext_vector_type(8)));
typedef short bf16x4 __attribute__((ext_vector_type(4)));
typedef float f32x4 __attribute__((ext_vector_type(4)));

// ws layout: [0..1] loss_sum/mask_count floats; weight image at byte WS_IMG_OFF.
#define WS_IMG_OFF 256
#define IMG_BYTES  119232          // 3*128*136*2 + 3*16*136*2 + 3*128*4 + 3*16*4
#define IMG_INSTS  117             // ceil(IMG_BYTES/1024); overshoot 576B lands in hids[0] (rewritten before read)

struct __align__(16) SMem {
  // ---- first 119232 bytes == prep image, copied verbatim ----
  short w1s[3][H_][LDW];   // W1^T bf16: [head][hidden j][input i]
  short w2s[3][16][LDW];   // W2^T bf16: [head][g pad16][hidden k]
  float b1s[3][H_];
  float b2s[3][16];
  // ---- per-wave hidden exchange (staging overshoot lands here; rewritten pre-read) ----
  short hids[WAVES][16][LDW];   // [wave][token][j]; write b64, read b128
  float red[WAVES][3];
};

__device__ __forceinline__ short f2bf(float f) {
  __hip_bfloat16 h = __float2bfloat16(f);
  union { __hip_bfloat16 h; short s; } u; u.h = h;
  return u.s;
}

__device__ __forceinline__ void async_copy16(void* lds_uniform, const void* gsrc_perlane) {
  __builtin_amdgcn_global_load_lds(
      (const __attribute__((address_space(1))) unsigned int*)gsrc_perlane,
      (__attribute__((address_space(3))) unsigned int*)lds_uniform,
      16, 0, 0);
}

__global__ __launch_bounds__(64) void init_kernel(float* out, float* ws) {
  int t = threadIdx.x;
  if (t < 33) out[t] = 0.0f;
  if (t < 2)  ws[t]  = 0.0f;
}

__global__ __launch_bounds__(64) void fin_kernel(float* out, const float* ws) {
  if (threadIdx.x == 0) out[32] = ws[0] / fmaxf(ws[1], 1.0f);
}

__global__ __launch_bounds__(256) void prep_kernel(
    const float* __restrict__ w1_0, const float* __restrict__ b1_0,
    const float* __restrict__ w2_0, const float* __restrict__ b2_0,
    const float* __restrict__ w1_1, const float* __restrict__ b1_1,
    const float* __restrict__ w2_1, const float* __restrict__ b2_1,
    const float* __restrict__ w1_2, const float* __restrict__ b1_2,
    const float* __restrict__ w2_2, const float* __restrict__ b2_2,
    short* __restrict__ img) {
  const float* w1p[3] = {w1_0, w1_1, w1_2};
  const float* w2p[3] = {w2_0, w2_1, w2_2};
  const float* b1p[3] = {b1_0, b1_1, b1_2};
  const float* b2p[3] = {b2_0, b2_1, b2_2};
  int t = blockIdx.x * 256 + threadIdx.x;
  int stride = gridDim.x * 256;
  for (int idx = t; idx < 3*H_*LDW; idx += stride) {
    int h = idx / (H_*LDW), rem = idx - h*(H_*LDW);
    int j = rem / LDW, i = rem - j*LDW;
    img[idx] = (i < H_) ? f2bf(w1p[h][i*H_ + j]) : (short)0;
  }
  for (int idx = t; idx < 3*16*LDW; idx += stride) {
    int h = idx / (16*LDW), rem = idx - h*(16*LDW);
    int g = rem / LDW, k = rem - g*LDW;
    img[3*H_*LDW + idx] = (g < G_ && k < H_) ? f2bf(w2p[h][k*G_ + g]) : (short)0;
  }
  float* bimg = (float*)(img + 3*H_*LDW + 3*16*LDW);
  if (t < 3*H_ + 3*16) {
    if (t < 3*H_) { int h = t >> 7, j = t & 127; bimg[t] = b1p[h][j]; }
    else { int i2 = t - 3*H_; int h = i2 >> 4, g = i2 & 15;
           bimg[t] = (g < G_) ? b2p[h][g] : 0.0f; }
  }
}

template<int PREP>
__global__ __launch_bounds__(THREADS, 2)   // 256-reg cap (128 arch / 128 acc split)
void rtm_main(const float* __restrict__ feat,
              const float* __restrict__ dist,
              const int* __restrict__ dmask,
              const float* __restrict__ img,
              const float* __restrict__ w1_0, const float* __restrict__ b1_0,
              const float* __restrict__ w2_0, const float* __restrict__ b2_0,
              const float* __restrict__ w1_1, const float* __restrict__ b1_1,
              const float* __restrict__ w2_1, const float* __restrict__ b2_1,
              const float* __restrict__ w1_2, const float* __restrict__ b1_2,
              const float* __restrict__ w2_2, const float* __restrict__ b2_2,
              float* __restrict__ out, float* __restrict__ ws) {
  __shared__ SMem sm;

  const int tid  = threadIdx.x;
  const int wave = tid >> 6;
  const int lane = tid & 63;
  const int q  = lane >> 4;
  const int lg = lane & 15;
  // wave owns 128 contiguous tokens: 4 tiles x (2 sub-tiles x 16 tokens)
  const long wbase = (long)blockIdx.x * TPB + (long)wave * (32*NITER);

  // ---- prologue: issue tile-0 loads (both 16-token sub-tiles) ----
  float4 fv[2][8];
  float dpre[2]; int mpre[2];
#pragma unroll
  for (int mt = 0; mt < 2; ++mt) {
    const float* fr = feat + (wbase + mt*16 + lg) * (long)H_;
#pragma unroll
    for (int c = 0; c < 4; ++c) {
      const float4* p = reinterpret_cast<const float4*>(fr + c*32 + q*8);
      fv[mt][2*c]   = p[0];
      fv[mt][2*c+1] = p[1];
    }
    dpre[mt] = dist[wbase + mt*16 + lg];
    mpre[mt] = dmask[wbase + mt*16 + lg];
  }

  // ---- stage weight image to LDS (async; once per CU) ----
  if constexpr (PREP) {
    char* smb = (char*)&sm;
    const char* gimg = (const char*)img;
    for (int i = wave; i < IMG_INSTS; i += WAVES)
      async_copy16(smb + i*1024, gimg + i*1024 + lane*16);
  } else {
    const float* w1p[3] = {w1_0, w1_1, w1_2};
    const float* w2p[3] = {w2_0, w2_1, w2_2};
    const float* b1p[3] = {b1_0, b1_1, b1_2};
    const float* b2p[3] = {b2_0, b2_1, b2_2};
    for (int h = 0; h < 3; ++h) {
      for (int idx = tid; idx < H_*H_; idx += THREADS) {
        int i = idx >> 7, j = idx & 127;
        sm.w1s[h][j][i] = f2bf(w1p[h][idx]);
      }
      for (int idx = tid; idx < 16*H_; idx += THREADS) {
        int g = idx >> 7, k = idx & 127;
        sm.w2s[h][g][k] = (g < G_) ? f2bf(w2p[h][(size_t)k*G_ + g]) : (short)0;
      }
      if (tid < H_) sm.b1s[h][tid] = b1p[h][tid];
      if (tid < 16) sm.b2s[h][tid] = (tid < G_) ? b2p[h][tid] : 0.0f;
    }
  }

  // ---- convert tile 0 while staging is in flight ----
  bf16x8 a1[2][4];   // B-frag: lane holds B[k=(lane>>4)*8+e][tok=lane&15]
#pragma unroll
  for (int mt = 0; mt < 2; ++mt)
#pragma unroll
    for (int c = 0; c < 4; ++c) {
      float4 lo = fv[mt][2*c], hi = fv[mt][2*c+1];
      bf16x8 a;
      a[0]=f2bf(lo.x); a[1]=f2bf(lo.y); a[2]=f2bf(lo.z); a[3]=f2bf(lo.w);
      a[4]=f2bf(hi.x); a[5]=f2bf(hi.y); a[6]=f2bf(hi.z); a[7]=f2bf(hi.w);
      a1[mt][c] = a;
    }

  __syncthreads();   // weights visible; drains global_load_lds

  float* out_score = out;
  float* out_pi = out + 33;
  float* out_mu = out + 33 + (size_t)TOKS*G_;
  float* out_sg = out + 33 + 2*(size_t)TOKS*G_;
  const float HLOG2PI = 0.91893853320467274f;
  const bool v0 = (q*4+0) < G_, v1 = (q*4+1) < G_, v2 = (q*4+2) < G_, v3 = (q*4+3) < G_;

  float accP = 0.f, accL = 0.f, accC = 0.f;

  // ---- pipelined tile loop: loads(s+1) fire under compute(s) ----
#pragma unroll
  for (int s = 0; s < NITER; ++s) {
    float dnx[2]; int mnx[2];
    if (s + 1 < NITER) {   // issue next tile's loads (fv drained by last convert)
#pragma unroll
      for (int mt = 0; mt < 2; ++mt) {
        const float* fr = feat + (wbase + (s+1)*32 + mt*16 + lg) * (long)H_;
#pragma unroll
        for (int c = 0; c < 4; ++c) {
          const float4* p = reinterpret_cast<const float4*>(fr + c*32 + q*8);
          fv[mt][2*c]   = p[0];
          fv[mt][2*c+1] = p[1];
        }
        dnx[mt] = dist[wbase + (s+1)*32 + mt*16 + lg];
        mnx[mt] = dmask[wbase + (s+1)*32 + mt*16 + lg];
      }
    }

    // ---- compute tile s: two sub-tiles share each W1 fragment ----
    f32x4 lgt[3][2];
#pragma unroll
    for (int h = 0; h < 3; ++h) {
      f32x4 acc[2][8];
#pragma unroll
      for (int mt = 0; mt < 2; ++mt)
#pragma unroll
        for (int nt = 0; nt < 8; ++nt) acc[mt][nt] = (f32x4){0.f,0.f,0.f,0.f};
#pragma unroll
      for (int c = 0; c < 4; ++c) {
#pragma unroll
        for (int nt = 0; nt < 8; ++nt) {
          bf16x8 wfr = *reinterpret_cast<const bf16x8*>(&sm.w1s[h][nt*16 + lg][c*32 + q*8]);
          acc[0][nt] = __builtin_amdgcn_mfma_f32_16x16x32_bf16(wfr, a1[0][c], acc[0][nt], 0, 0, 0);
          acc[1][nt] = __builtin_amdgcn_mfma_f32_16x16x32_bf16(wfr, a1[1][c], acc[1][nt], 0, 0, 0);
        }
      }
#pragma unroll
      for (int mt = 0; mt < 2; ++mt) {
        // bias+relu+pack straight to wave-private LDS: D row = j = q*4+r
        // (4 contiguous j for token lg) -> one ds_write_b64 per nt
#pragma unroll
        for (int nt = 0; nt < 8; ++nt) {
          f32x4 b1v = *reinterpret_cast<const f32x4*>(&sm.b1s[h][nt*16 + q*4]);
          bf16x4 pkv;
#pragma unroll
          for (int r = 0; r < 4; ++r)
            pkv[r] = f2bf(fmaxf(acc[mt][nt][r] + b1v[r], 0.0f));
          *reinterpret_cast<bf16x4*>(&sm.hids[wave][lg][nt*16 + q*4]) = pkv;
        }
        // layer 2: B-frag read directly from hids (same-wave LDS FIFO, no barrier,
        // no bpermute): lane reads hidden[j=c*32+q*8+e][tok=lg]
        f32x4 lacc = (f32x4){0.f,0.f,0.f,0.f};
#pragma unroll
        for (int c = 0; c < 4; ++c) {
          bf16x8 hfr  = *reinterpret_cast<const bf16x8*>(&sm.hids[wave][lg][c*32 + q*8]);
          bf16x8 w2fr = *reinterpret_cast<const bf16x8*>(&sm.w2s[h][lg][c*32 + q*8]);
          lacc = __builtin_amdgcn_mfma_f32_16x16x32_bf16(w2fr, hfr, lacc, 0, 0, 0);
        }
        f32x4 b2v = *reinterpret_cast<const f32x4*>(&sm.b2s[h][q*4]);
        lgt[h][mt] = lacc + b2v;   // row = g = q*4+r, col = token = lg
      }
    }

    // ---- epilogue tile s (both sub-tiles) ----
#pragma unroll
    for (int mt = 0; mt < 2; ++mt) {
      long tok = wbase + s*32 + mt*16 + lg;
      float d  = dpre[mt];
      bool  mk = (mpre[mt] != 0) && (d <= 8.0f);
      f32x4 LP = lgt[0][mt], LS = lgt[1][mt], LM = lgt[2][mt];

      float vm = v0 ? LP[0] : -INFINITY;
      if (v1) vm = fmaxf(vm, LP[1]);
      if (v2) vm = fmaxf(vm, LP[2]);
      if (v3) vm = fmaxf(vm, LP[3]);
      vm = fmaxf(vm, __shfl_xor(vm, 16));
      vm = fmaxf(vm, __shfl_xor(vm, 32));
      float e0 = v0 ? __expf(LP[0]-vm) : 0.f;
      float e1 = v1 ? __expf(LP[1]-vm) : 0.f;
      float e2 = v2 ? __expf(LP[2]-vm) : 0.f;
      float e3 = v3 ? __expf(LP[3]-vm) : 0.f;
      float ssum = e0+e1+e2+e3;
      ssum += __shfl_xor(ssum, 16);
      ssum += __shfl_xor(ssum, 32);
      float inv = 1.0f / ssum;
      float pi[4] = {e0*inv, e1*inv, e2*inv, e3*inv};

      float sg[4], mu[4], ll[4];
#pragma unroll
      for (int r = 0; r < 4; ++r) {
        sg[r] = (LS[r] > 0.f) ? (LS[r] + 1.4f) : (__expf(LS[r]) + 0.4f);
        mu[r] = (LM[r] > 0.f) ? (LM[r] + 1.0f) : __expf(LM[r]);
        float z = (d - mu[r]) / sg[r];
        ll[r] = -0.5f*z*z - __logf(sg[r]) - HLOG2PI;
      }

      if (q*4 < G_) {
        size_t o = (size_t)tok*G_ + q*4;
        *reinterpret_cast<float2*>(&out_pi[o]) = make_float2(pi[0], pi[1]);
        *reinterpret_cast<float2*>(&out_mu[o]) = make_float2(mu[0], mu[1]);
        *reinterpret_cast<float2*>(&out_sg[o]) = make_float2(sg[0], sg[1]);
        if (q*4+2 < G_) {
          *reinterpret_cast<float2*>(&out_pi[o+2]) = make_float2(pi[2], pi[3]);
          *reinterpret_cast<float2*>(&out_mu[o+2]) = make_float2(mu[2], mu[3]);
          *reinterpret_cast<float2*>(&out_sg[o+2]) = make_float2(sg[2], sg[3]);
        }
      }

      float a0 = v0 ? (__logf(pi[0]+1e-10f) + ll[0]) : -INFINITY;
      float a1x= v1 ? (__logf(pi[1]+1e-10f) + ll[1]) : -INFINITY;
      float a2 = v2 ? (__logf(pi[2]+1e-10f) + ll[2]) : -INFINITY;
      float a3 = v3 ? (__logf(pi[3]+1e-10f) + ll[3]) : -INFINITY;
      float m2 = fmaxf(fmaxf(a0,a1x), fmaxf(a2,a3));
      m2 = fmaxf(m2, __shfl_xor(m2, 16));
      m2 = fmaxf(m2, __shfl_xor(m2, 32));
      float s2 = (v0?__expf(a0-m2):0.f) + (v1?__expf(a1x-m2):0.f)
               + (v2?__expf(a2-m2):0.f) + (v3?__expf(a3-m2):0.f);
      s2 += __shfl_xor(s2, 16);
      s2 += __shfl_xor(s2, 32);
      float closs = -(m2 + __logf(s2));

      float s3 = (v0?__expf(ll[0])*pi[0]:0.f) + (v1?__expf(ll[1])*pi[1]:0.f)
               + (v2?__expf(ll[2])*pi[2]:0.f) + (v3?__expf(ll[3])*pi[3]:0.f);
      s3 += __shfl_xor(s3, 16);
      s3 += __shfl_xor(s3, 32);
      float prob = s3 / (d*d + 1e-10f);

      if (lane < 16 && mk) { accP += prob; accL += closs; accC += 1.f; }
    }

    // ---- convert next tile (loads had the whole compute+epilogue to land) ----
    if (s + 1 < NITER) {
#pragma unroll
      for (int mt = 0; mt < 2; ++mt) {
#pragma unroll
        for (int c = 0; c < 4; ++c) {
          float4 lo = fv[mt][2*c], hi = fv[mt][2*c+1];
          bf16x8 a;
          a[0]=f2bf(lo.x); a[1]=f2bf(lo.y); a[2]=f2bf(lo.z); a[3]=f2bf(lo.w);
          a[4]=f2bf(hi.x); a[5]=f2bf(hi.y); a[6]=f2bf(hi.z); a[7]=f2bf(hi.w);
          a1[mt][c] = a;
        }
        dpre[mt] = dnx[mt]; mpre[mt] = mnx[mt];
      }
    }
  }

  // ---- block reduce; block lies entirely in one batch b ----
  accP += __shfl_xor(accP, 1); accP += __shfl_xor(accP, 2);
  accP += __shfl_xor(accP, 4); accP += __shfl_xor(accP, 8);
  accL += __shfl_xor(accL, 1); accL += __shfl_xor(accL, 2);
  accL += __shfl_xor(accL, 4); accL += __shfl_xor(accL, 8);
  accC += __shfl_xor(accC, 1); accC += __shfl_xor(accC, 2);
  accC += __shfl_xor(accC, 4); accC += __shfl_xor(accC, 8);
  if (lane == 0) { sm.red[wave][0] = accP; sm.red[wave][1] = accL; sm.red[wave][2] = accC; }
  __syncthreads();
  if (tid == 0) {
    float sP = 0.f, sL = 0.f, sC = 0.f;
    for (int w = 0; w < WAVES; ++w) { sP += sm.red[w][0]; sL += sm.red[w][1]; sC += sm.red[w][2]; }
    int b = blockIdx.x >> 3;   // 8 blocks per batch (1024 tokens/block)
    atomicAdd(&out_score[b], sP);
    atomicAdd(&ws[0], sL);
    atomicAdd(&ws[1], sC);
  }
}

extern "C" void kernel_launch(void* const* d_in, const int* in_sizes, int n_in,
                              void* d_out, int out_size, void* d_ws, size_t ws_size,
                              hipStream_t stream) {
  const float* feat = (const float*)d_in[0];
  const float* dist = (const float*)d_in[1];
  const int* dmask = (const int*)d_in[2];
  float* out = (float*)d_out;
  float* ws  = (float*)d_ws;

  hipLaunchKernelGGL(init_kernel, dim3(1), dim3(64), 0, stream, out, ws);

  bool prep_ok = (ws_size >= (size_t)(WS_IMG_OFF + IMG_INSTS*1024));
  if (prep_ok) {
    short* img = (short*)((char*)d_ws + WS_IMG_OFF);
    hipLaunchKernelGGL(prep_kernel, dim3(116), dim3(256), 0, stream,
        (const float*)d_in[3],  (const float*)d_in[4],  (const float*)d_in[5],  (const float*)d_in[6],
        (const float*)d_in[7],  (const float*)d_in[8],  (const float*)d_in[9],  (const float*)d_in[10],
        (const float*)d_in[11], (const float*)d_in[12], (const float*)d_in[13], (const float*)d_in[14],
        img);
    hipLaunchKernelGGL((rtm_main<1>), dim3(TOKS/TPB), dim3(THREADS), 0, stream,
        feat, dist, dmask, (const float*)img,
        (const float*)d_in[3],  (const float*)d_in[4],  (const float*)d_in[5],  (const float*)d_in[6],
        (const float*)d_in[7],  (const float*)d_in[8],  (const float*)d_in[9],  (const float*)d_in[10],
        (const float*)d_in[11], (const float*)d_in[12], (const float*)d_in[13], (const float*)d_in[14],
        out, ws);
  } else {
    hipLaunchKernelGGL((rtm_main<0>), dim3(TOKS/TPB), dim3(THREADS), 0, stream,
        feat, dist, dmask, (const float*)nullptr,
        (const float*)d_in[3],  (const float*)d_in[4],  (const float*)d_in[5],  (const float*)d_in[6],
        (const float*)d_in[7],  (const float*)d_in[8],  (const float*)d_in[9],  (const float*)d_in[10],
        (const float*)d_in[11], (const float*)d_in[12], (const float*)d_in[13], (const float*)d_in[14],
        out, ws);
  }

  hipLaunchKernelGGL(fin_kernel, dim3(1), dim3(64), 0, stream, out, ws);
}

// Round 13
// 65.853 us; speedup vs baseline: 7.9395x; 1.0448x over previous
//
#include <hip/hip_runtime.h>
#include <hip/hip_bf16.h>
#include <math.h>

#define B_   32
#define N_   8192
#define H_   128
#define G_   10
#define TOKS (B_*N_)
#define THREADS 512
#define WAVES 8
#define NITER 4
#define TPB 1024   // 8 waves x 32 tok/tile x 4 tiles -> grid = exactly 256 blocks (1/CU)
#define LDW 136    // padded LDS row stride in shorts (272B, 16B-aligned rows)

typedef short bf16x8 __attribute__((ext_vector_type(8)));
typedef short bf16x4 __attribute__((ext_vector_type(4)));
typedef float f32x4 __attribute__((ext_vector_type(4)));

// ws layout: [0..1] loss_sum/mask_count floats; weight image at byte WS_IMG_OFF.
#define WS_IMG_OFF 256
#define IMG_BYTES  119232          // 3*128*136*2 + 3*16*136*2 + 3*128*4 + 3*16*4
#define IMG_INSTS  117             // ceil(IMG_BYTES/1024); overshoot 576B lands in red/pad (safe)

struct __align__(16) SMem {
  // ---- first 119232 bytes == prep image, copied verbatim ----
  short w1s[3][H_][LDW];   // W1^T bf16: [head][hidden j][input i]
  short w2s[3][16][LDW];   // W2^T bf16: [head][g pad16][hidden k]
  float b1s[3][H_];
  float b2s[3][16];
  // ---- scratch (staging overshoot scribbles here pre-barrier; written post-compute) ----
  float red[WAVES][3];
  char  pad[640];
};

__device__ __forceinline__ short f2bf(float f) {
  __hip_bfloat16 h = __float2bfloat16(f);
  union { __hip_bfloat16 h; short s; } u; u.h = h;
  return u.s;
}

__device__ __forceinline__ void async_copy16(void* lds_uniform, const void* gsrc_perlane) {
  __builtin_amdgcn_global_load_lds(
      (const __attribute__((address_space(1))) unsigned int*)gsrc_perlane,
      (__attribute__((address_space(3))) unsigned int*)lds_uniform,
      16, 0, 0);
}

__global__ __launch_bounds__(64) void init_kernel(float* out, float* ws) {
  int t = threadIdx.x;
  if (t < 33) out[t] = 0.0f;
  if (t < 2)  ws[t]  = 0.0f;
}

__global__ __launch_bounds__(64) void fin_kernel(float* out, const float* ws) {
  if (threadIdx.x == 0) out[32] = ws[0] / fmaxf(ws[1], 1.0f);
}

__global__ __launch_bounds__(256) void prep_kernel(
    const float* __restrict__ w1_0, const float* __restrict__ b1_0,
    const float* __restrict__ w2_0, const float* __restrict__ b2_0,
    const float* __restrict__ w1_1, const float* __restrict__ b1_1,
    const float* __restrict__ w2_1, const float* __restrict__ b2_1,
    const float* __restrict__ w1_2, const float* __restrict__ b1_2,
    const float* __restrict__ w2_2, const float* __restrict__ b2_2,
    short* __restrict__ img) {
  const float* w1p[3] = {w1_0, w1_1, w1_2};
  const float* w2p[3] = {w2_0, w2_1, w2_2};
  const float* b1p[3] = {b1_0, b1_1, b1_2};
  const float* b2p[3] = {b2_0, b2_1, b2_2};
  int t = blockIdx.x * 256 + threadIdx.x;
  int stride = gridDim.x * 256;
  for (int idx = t; idx < 3*H_*LDW; idx += stride) {
    int h = idx / (H_*LDW), rem = idx - h*(H_*LDW);
    int j = rem / LDW, i = rem - j*LDW;
    img[idx] = (i < H_) ? f2bf(w1p[h][i*H_ + j]) : (short)0;
  }
  for (int idx = t; idx < 3*16*LDW; idx += stride) {
    int h = idx / (16*LDW), rem = idx - h*(16*LDW);
    int g = rem / LDW, k = rem - g*LDW;
    img[3*H_*LDW + idx] = (g < G_ && k < H_) ? f2bf(w2p[h][k*G_ + g]) : (short)0;
  }
  float* bimg = (float*)(img + 3*H_*LDW + 3*16*LDW);
  if (t < 3*H_ + 3*16) {
    if (t < 3*H_) { int h = t >> 7, j = t & 127; bimg[t] = b1p[h][j]; }
    else { int i2 = t - 3*H_; int h = i2 >> 4, g = i2 & 15;
           bimg[t] = (g < G_) ? b2p[h][g] : 0.0f; }
  }
}

template<int PREP>
__global__ __launch_bounds__(THREADS, 2)   // 256-reg cap
void rtm_main(const float* __restrict__ feat,
              const float* __restrict__ dist,
              const int* __restrict__ dmask,
              const float* __restrict__ img,
              const float* __restrict__ w1_0, const float* __restrict__ b1_0,
              const float* __restrict__ w2_0, const float* __restrict__ b2_0,
              const float* __restrict__ w1_1, const float* __restrict__ b1_1,
              const float* __restrict__ w2_1, const float* __restrict__ b2_1,
              const float* __restrict__ w1_2, const float* __restrict__ b1_2,
              const float* __restrict__ w2_2, const float* __restrict__ b2_2,
              float* __restrict__ out, float* __restrict__ ws) {
  __shared__ SMem sm;

  const int tid  = threadIdx.x;
  const int wave = tid >> 6;
  const int lane = tid & 63;
  const int q  = lane >> 4;
  const int lg = lane & 15;
  // wave owns 128 contiguous tokens: 4 tiles x (2 sub-tiles x 16 tokens)
  const long wbase = (long)blockIdx.x * TPB + (long)wave * (32*NITER);

  // ---- prologue: issue tile-0 loads (both 16-token sub-tiles) ----
  float4 fv[2][8];
  float dpre[2]; int mpre[2];
#pragma unroll
  for (int mt = 0; mt < 2; ++mt) {
    const float* fr = feat + (wbase + mt*16 + lg) * (long)H_;
#pragma unroll
    for (int c = 0; c < 4; ++c) {
      const float4* p = reinterpret_cast<const float4*>(fr + c*32 + q*8);
      fv[mt][2*c]   = p[0];
      fv[mt][2*c+1] = p[1];
    }
    dpre[mt] = dist[wbase + mt*16 + lg];
    mpre[mt] = dmask[wbase + mt*16 + lg];
  }

  // ---- stage weight image to LDS (async; once per CU) ----
  if constexpr (PREP) {
    char* smb = (char*)&sm;
    const char* gimg = (const char*)img;
    for (int i = wave; i < IMG_INSTS; i += WAVES)
      async_copy16(smb + i*1024, gimg + i*1024 + lane*16);
  } else {
    const float* w1p[3] = {w1_0, w1_1, w1_2};
    const float* w2p[3] = {w2_0, w2_1, w2_2};
    const float* b1p[3] = {b1_0, b1_1, b1_2};
    const float* b2p[3] = {b2_0, b2_1, b2_2};
    for (int h = 0; h < 3; ++h) {
      for (int idx = tid; idx < H_*H_; idx += THREADS) {
        int i = idx >> 7, j = idx & 127;
        sm.w1s[h][j][i] = f2bf(w1p[h][idx]);
      }
      for (int idx = tid; idx < 16*H_; idx += THREADS) {
        int g = idx >> 7, k = idx & 127;
        sm.w2s[h][g][k] = (g < G_) ? f2bf(w2p[h][(size_t)k*G_ + g]) : (short)0;
      }
      if (tid < H_) sm.b1s[h][tid] = b1p[h][tid];
      if (tid < 16) sm.b2s[h][tid] = (tid < G_) ? b2p[h][tid] : 0.0f;
    }
  }

  // ---- convert tile 0 while staging is in flight ----
  bf16x8 a1[2][4];   // B-frag (K=32): lane holds B[k=(lane>>4)*8+e][tok=lane&15]
#pragma unroll
  for (int mt = 0; mt < 2; ++mt)
#pragma unroll
    for (int c = 0; c < 4; ++c) {
      float4 lo = fv[mt][2*c], hi = fv[mt][2*c+1];
      bf16x8 a;
      a[0]=f2bf(lo.x); a[1]=f2bf(lo.y); a[2]=f2bf(lo.z); a[3]=f2bf(lo.w);
      a[4]=f2bf(hi.x); a[5]=f2bf(hi.y); a[6]=f2bf(hi.z); a[7]=f2bf(hi.w);
      a1[mt][c] = a;
    }

  __syncthreads();   // weights visible; drains global_load_lds

  float* out_score = out;
  float* out_pi = out + 33;
  float* out_mu = out + 33 + (size_t)TOKS*G_;
  float* out_sg = out + 33 + 2*(size_t)TOKS*G_;
  const float HLOG2PI = 0.91893853320467274f;
  const bool v0 = (q*4+0) < G_, v1 = (q*4+1) < G_, v2 = (q*4+2) < G_, v3 = (q*4+3) < G_;

  float accP = 0.f, accL = 0.f, accC = 0.f;

  // ---- pipelined tile loop: loads(s+1) fire under compute(s) ----
#pragma unroll
  for (int s = 0; s < NITER; ++s) {
    float dnx[2]; int mnx[2];
    if (s + 1 < NITER) {
#pragma unroll
      for (int mt = 0; mt < 2; ++mt) {
        const float* fr = feat + (wbase + (s+1)*32 + mt*16 + lg) * (long)H_;
#pragma unroll
        for (int c = 0; c < 4; ++c) {
          const float4* p = reinterpret_cast<const float4*>(fr + c*32 + q*8);
          fv[mt][2*c]   = p[0];
          fv[mt][2*c+1] = p[1];
        }
        dnx[mt] = dist[wbase + (s+1)*32 + mt*16 + lg];
        mnx[mt] = dmask[wbase + (s+1)*32 + mt*16 + lg];
      }
    }

    // ---- compute tile s ----
    f32x4 lgt[3][2];
#pragma unroll
    for (int h = 0; h < 3; ++h) {
      // W2^T A-frags for K=16 layer-2 (loaded once per h, shared across mt):
      // lane holds W2^T[g=lg][k=nt*16+q*4+e], e=0..3  -> ds_read_b64
      bf16x4 w2fr[8];
#pragma unroll
      for (int nt = 0; nt < 8; ++nt)
        w2fr[nt] = *reinterpret_cast<const bf16x4*>(&sm.w2s[h][lg][nt*16 + q*4]);

      // layer 1: W1 fragment read once feeds both sub-tiles
      f32x4 acc[2][8];
#pragma unroll
      for (int mt = 0; mt < 2; ++mt)
#pragma unroll
        for (int nt = 0; nt < 8; ++nt) acc[mt][nt] = (f32x4){0.f,0.f,0.f,0.f};
#pragma unroll
      for (int c = 0; c < 4; ++c) {
#pragma unroll
        for (int nt = 0; nt < 8; ++nt) {
          bf16x8 wfr = *reinterpret_cast<const bf16x8*>(&sm.w1s[h][nt*16 + lg][c*32 + q*8]);
          acc[0][nt] = __builtin_amdgcn_mfma_f32_16x16x32_bf16(wfr, a1[0][c], acc[0][nt], 0, 0, 0);
          acc[1][nt] = __builtin_amdgcn_mfma_f32_16x16x32_bf16(wfr, a1[1][c], acc[1][nt], 0, 0, 0);
        }
      }
#pragma unroll
      for (int mt = 0; mt < 2; ++mt) {
        // layer 2 entirely in registers: D[j=q*4+r][tok=lg] == K=16 B-frag layout
        // B[k=(lane>>4)*4+j][col=lane&15] for k-chunk nt. No LDS round trip.
        f32x4 lacc = (f32x4){0.f,0.f,0.f,0.f};
#pragma unroll
        for (int nt = 0; nt < 8; ++nt) {
          f32x4 b1v = *reinterpret_cast<const f32x4*>(&sm.b1s[h][nt*16 + q*4]);
          bf16x4 pkv;
#pragma unroll
          for (int r = 0; r < 4; ++r)
            pkv[r] = f2bf(fmaxf(acc[mt][nt][r] + b1v[r], 0.0f));
          lacc = __builtin_amdgcn_mfma_f32_16x16x16bf16_1k(w2fr[nt], pkv, lacc, 0, 0, 0);
        }
        f32x4 b2v = *reinterpret_cast<const f32x4*>(&sm.b2s[h][q*4]);
        lgt[h][mt] = lacc + b2v;   // row = g = q*4+r, col = token = lg
      }
    }

    // ---- epilogue tile s (both sub-tiles) ----
#pragma unroll
    for (int mt = 0; mt < 2; ++mt) {
      long tok = wbase + s*32 + mt*16 + lg;
      float d  = dpre[mt];
      bool  mk = (mpre[mt] != 0) && (d <= 8.0f);
      f32x4 LP = lgt[0][mt], LS = lgt[1][mt], LM = lgt[2][mt];

      float vm = v0 ? LP[0] : -INFINITY;
      if (v1) vm = fmaxf(vm, LP[1]);
      if (v2) vm = fmaxf(vm, LP[2]);
      if (v3) vm = fmaxf(vm, LP[3]);
      vm = fmaxf(vm, __shfl_xor(vm, 16));
      vm = fmaxf(vm, __shfl_xor(vm, 32));
      float e0 = v0 ? __expf(LP[0]-vm) : 0.f;
      float e1 = v1 ? __expf(LP[1]-vm) : 0.f;
      float e2 = v2 ? __expf(LP[2]-vm) : 0.f;
      float e3 = v3 ? __expf(LP[3]-vm) : 0.f;
      float ssum = e0+e1+e2+e3;
      ssum += __shfl_xor(ssum, 16);
      ssum += __shfl_xor(ssum, 32);
      float inv = 1.0f / ssum;
      float pi[4] = {e0*inv, e1*inv, e2*inv, e3*inv};

      float sg[4], mu[4], ll[4];
#pragma unroll
      for (int r = 0; r < 4; ++r) {
        sg[r] = (LS[r] > 0.f) ? (LS[r] + 1.4f) : (__expf(LS[r]) + 0.4f);
        mu[r] = (LM[r] > 0.f) ? (LM[r] + 1.0f) : __expf(LM[r]);
        float z = (d - mu[r]) / sg[r];
        ll[r] = -0.5f*z*z - __logf(sg[r]) - HLOG2PI;
      }

      if (q*4 < G_) {
        size_t o = (size_t)tok*G_ + q*4;
        *reinterpret_cast<float2*>(&out_pi[o]) = make_float2(pi[0], pi[1]);
        *reinterpret_cast<float2*>(&out_mu[o]) = make_float2(mu[0], mu[1]);
        *reinterpret_cast<float2*>(&out_sg[o]) = make_float2(sg[0], sg[1]);
        if (q*4+2 < G_) {
          *reinterpret_cast<float2*>(&out_pi[o+2]) = make_float2(pi[2], pi[3]);
          *reinterpret_cast<float2*>(&out_mu[o+2]) = make_float2(mu[2], mu[3]);
          *reinterpret_cast<float2*>(&out_sg[o+2]) = make_float2(sg[2], sg[3]);
        }
      }

      float a0 = v0 ? (__logf(pi[0]+1e-10f) + ll[0]) : -INFINITY;
      float a1x= v1 ? (__logf(pi[1]+1e-10f) + ll[1]) : -INFINITY;
      float a2 = v2 ? (__logf(pi[2]+1e-10f) + ll[2]) : -INFINITY;
      float a3 = v3 ? (__logf(pi[3]+1e-10f) + ll[3]) : -INFINITY;
      float m2 = fmaxf(fmaxf(a0,a1x), fmaxf(a2,a3));
      m2 = fmaxf(m2, __shfl_xor(m2, 16));
      m2 = fmaxf(m2, __shfl_xor(m2, 32));
      float s2 = (v0?__expf(a0-m2):0.f) + (v1?__expf(a1x-m2):0.f)
               + (v2?__expf(a2-m2):0.f) + (v3?__expf(a3-m2):0.f);
      s2 += __shfl_xor(s2, 16);
      s2 += __shfl_xor(s2, 32);
      float closs = -(m2 + __logf(s2));

      float s3 = (v0?__expf(ll[0])*pi[0]:0.f) + (v1?__expf(ll[1])*pi[1]:0.f)
               + (v2?__expf(ll[2])*pi[2]:0.f) + (v3?__expf(ll[3])*pi[3]:0.f);
      s3 += __shfl_xor(s3, 16);
      s3 += __shfl_xor(s3, 32);
      float prob = s3 / (d*d + 1e-10f);

      if (lane < 16 && mk) { accP += prob; accL += closs; accC += 1.f; }
    }

    // ---- convert next tile ----
    if (s + 1 < NITER) {
#pragma unroll
      for (int mt = 0; mt < 2; ++mt) {
#pragma unroll
        for (int c = 0; c < 4; ++c) {
          float4 lo = fv[mt][2*c], hi = fv[mt][2*c+1];
          bf16x8 a;
          a[0]=f2bf(lo.x); a[1]=f2bf(lo.y); a[2]=f2bf(lo.z); a[3]=f2bf(lo.w);
          a[4]=f2bf(hi.x); a[5]=f2bf(hi.y); a[6]=f2bf(hi.z); a[7]=f2bf(hi.w);
          a1[mt][c] = a;
        }
        dpre[mt] = dnx[mt]; mpre[mt] = mnx[mt];
      }
    }
  }

  // ---- block reduce; block lies entirely in one batch b ----
  accP += __shfl_xor(accP, 1); accP += __shfl_xor(accP, 2);
  accP += __shfl_xor(accP, 4); accP += __shfl_xor(accP, 8);
  accL += __shfl_xor(accL, 1); accL += __shfl_xor(accL, 2);
  accL += __shfl_xor(accL, 4); accL += __shfl_xor(accL, 8);
  accC += __shfl_xor(accC, 1); accC += __shfl_xor(accC, 2);
  accC += __shfl_xor(accC, 4); accC += __shfl_xor(accC, 8);
  if (lane == 0) { sm.red[wave][0] = accP; sm.red[wave][1] = accL; sm.red[wave][2] = accC; }
  __syncthreads();
  if (tid == 0) {
    float sP = 0.f, sL = 0.f, sC = 0.f;
    for (int w = 0; w < WAVES; ++w) { sP += sm.red[w][0]; sL += sm.red[w][1]; sC += sm.red[w][2]; }
    int b = blockIdx.x >> 3;   // 8 blocks per batch (1024 tokens/block)
    atomicAdd(&out_score[b], sP);
    atomicAdd(&ws[0], sL);
    atomicAdd(&ws[1], sC);
  }
}

extern "C" void kernel_launch(void* const* d_in, const int* in_sizes, int n_in,
                              void* d_out, int out_size, void* d_ws, size_t ws_size,
                              hipStream_t stream) {
  const float* feat = (const float*)d_in[0];
  const float* dist = (const float*)d_in[1];
  const int* dmask = (const int*)d_in[2];
  float* out = (float*)d_out;
  float* ws  = (float*)d_ws;

  hipLaunchKernelGGL(init_kernel, dim3(1), dim3(64), 0, stream, out, ws);

  bool prep_ok = (ws_size >= (size_t)(WS_IMG_OFF + IMG_INSTS*1024));
  if (prep_ok) {
    short* img = (short*)((char*)d_ws + WS_IMG_OFF);
    hipLaunchKernelGGL(prep_kernel, dim3(116), dim3(256), 0, stream,
        (const float*)d_in[3],  (const float*)d_in[4],  (const float*)d_in[5],  (const float*)d_in[6],
        (const float*)d_in[7],  (const float*)d_in[8],  (const float*)d_in[9],  (const float*)d_in[10],
        (const float*)d_in[11], (const float*)d_in[12], (const float*)d_in[13], (const float*)d_in[14],
        img);
    hipLaunchKernelGGL((rtm_main<1>), dim3(TOKS/TPB), dim3(THREADS), 0, stream,
        feat, dist, dmask, (const float*)img,
        (const float*)d_in[3],  (const float*)d_in[4],  (const float*)d_in[5],  (const float*)d_in[6],
        (const float*)d_in[7],  (const float*)d_in[8],  (const float*)d_in[9],  (const float*)d_in[10],
        (const float*)d_in[11], (const float*)d_in[12], (const float*)d_in[13], (const float*)d_in[14],
        out, ws);
  } else {
    hipLaunchKernelGGL((rtm_main<0>), dim3(TOKS/TPB), dim3(THREADS), 0, stream,
        feat, dist, dmask, (const float*)nullptr,
        (const float*)d_in[3],  (const float*)d_in[4],  (const float*)d_in[5],  (const float*)d_in[6],
        (const float*)d_in[7],  (const float*)d_in[8],  (const float*)d_in[9],  (const float*)d_in[10],
        (const float*)d_in[11], (const float*)d_in[12], (const float*)d_in[13], (const float*)d_in[14],
        out, ws);
  }

  hipLaunchKernelGGL(fin_kernel, dim3(1), dim3(64), 0, stream, out, ws);
}